// Round 1
// baseline (799.739 us; speedup 1.0000x reference)
//
#include <hip/hip_runtime.h>
#include <hip/hip_bf16.h>

// Problem constants (match reference)
#define B_     2
#define CTX_   1024
#define TGT_   256
#define DM_    512
#define L_     1280          // CTX + TGT
#define DI_    1024          // EXPAND * D_MODEL
#define DS_    16            // D_STATE
#define DCONV_ 4
#define NL_    2
#define DTR_   32            // DT_RANK
#define MROWS_ (B_*L_)       // 2560
#define NC_    20            // scan chunks
#define CL_    64            // chunk length (NC_*CL_ == L_)

__device__ __forceinline__ float sigmoidf_(float v){ return 1.f/(1.f+__expf(-v)); }
__device__ __forceinline__ float siluf_(float v){ return v*sigmoidf_(v); }
__device__ __forceinline__ float softplusf_(float v){ return (v>20.f)?v:log1pf(__expf(v)); }

// ---------------- small data-movement kernels ----------------

__global__ __launch_bounds__(256) void k_copy_ctx(const float* __restrict__ ctx, float* __restrict__ x){
    int i = blockIdx.x*256 + threadIdx.x;        // B*CTX*DM = 1,048,576
    int d = i % DM_;
    int l = (i/DM_) % CTX_;
    int b = i/(DM_*CTX_);
    x[((size_t)(b*L_+l))*DM_ + d] = ctx[i];
}

__global__ __launch_bounds__(256) void k_build_tc(const float* __restrict__ te, const float* __restrict__ ve,
                                                  float* __restrict__ tc){
    int i = blockIdx.x*256 + threadIdx.x;        // B*TGT*2DM = 524,288
    int k = i % (2*DM_);
    int r = i / (2*DM_);                          // b*TGT + t
    tc[i] = (k < DM_) ? te[(size_t)r*DM_ + k] : ve[(size_t)r*DM_ + (k-DM_)];
}

__global__ __launch_bounds__(256) void k_scatter_pos(const float* __restrict__ pos, float* __restrict__ x){
    int i = blockIdx.x*256 + threadIdx.x;        // B*TGT*DM = 262,144
    int d = i % DM_;
    int r = i / DM_;                              // b*TGT + t
    int b = r / TGT_, t = r % TGT_;
    x[((size_t)(b*L_+CTX_+t))*DM_ + d] = pos[i];
}

// depthwise causal conv (kernel 4) + bias + silu;  xc = xz[:, :, 0:1024]
__global__ __launch_bounds__(256) void k_conv_silu(const float* __restrict__ xz, const float* __restrict__ cw,
                                                   const float* __restrict__ cb, float* __restrict__ u){
    int i = blockIdx.x*256 + threadIdx.x;        // MROWS_*DI_ = 2,621,440
    int d = i % DI_;
    int l = (i/DI_) % L_;
    int b = i/(DI_*L_);
    const float* base = xz + (size_t)b*L_*2048 + d;
    float acc = cb[d];
    #pragma unroll
    for (int k=0;k<DCONV_;++k){
        int ll = l-3+k;
        if (ll >= 0) acc = fmaf(base[(size_t)ll*2048], cw[d*DCONV_+k], acc);
    }
    u[i] = siluf_(acc);
}

// ---------------- generic fp32 tiled GEMM:  C[M,N] = A[M,K] * B[N,K]^T (+bias)(+C) ----------------
// Requirements used here: M%64==0, N%64==0, K%32==0 (true for every call site).
template<bool ACC>
__global__ __launch_bounds__(256) void k_mm(const float* __restrict__ A, int lda,
                                            const float* __restrict__ Bw, int ldb,
                                            float* __restrict__ C, int ldc,
                                            const float* __restrict__ bias, int K){
    __shared__ float As[32][68];   // [k][m]
    __shared__ float Bs[32][68];   // [k][n]
    int tid = threadIdx.x;
    int bm = blockIdx.y*64, bn = blockIdx.x*64;
    int tx = tid & 15, ty = tid >> 4;
    float acc[4][4] = {};
    for (int k0 = 0; k0 < K; k0 += 32){
        #pragma unroll
        for (int i=0;i<2;++i){
            int slot = tid + i*256;              // 0..511
            int r  = slot >> 3;                  // 0..63
            int kv = (slot & 7) << 2;            // 0..28
            float4 a4 = *(const float4*)&A [(size_t)(bm+r)*lda + k0 + kv];
            As[kv+0][r]=a4.x; As[kv+1][r]=a4.y; As[kv+2][r]=a4.z; As[kv+3][r]=a4.w;
            float4 b4 = *(const float4*)&Bw[(size_t)(bn+r)*ldb + k0 + kv];
            Bs[kv+0][r]=b4.x; Bs[kv+1][r]=b4.y; Bs[kv+2][r]=b4.z; Bs[kv+3][r]=b4.w;
        }
        __syncthreads();
        #pragma unroll
        for (int k=0;k<32;++k){
            float4 av = *(const float4*)&As[k][ty*4];
            float4 bv = *(const float4*)&Bs[k][tx*4];
            float a_[4]={av.x,av.y,av.z,av.w};
            float b_[4]={bv.x,bv.y,bv.z,bv.w};
            #pragma unroll
            for (int ii=0;ii<4;++ii)
                #pragma unroll
                for (int jj=0;jj<4;++jj)
                    acc[ii][jj] = fmaf(a_[ii], b_[jj], acc[ii][jj]);
        }
        __syncthreads();
    }
    #pragma unroll
    for (int ii=0;ii<4;++ii){
        int m = bm + ty*4 + ii;
        #pragma unroll
        for (int jj=0;jj<4;++jj){
            int n = bn + tx*4 + jj;
            float v = acc[ii][jj];
            if (bias) v += bias[n];
            if (ACC)  v += C[(size_t)m*ldc + n];
            C[(size_t)m*ldc + n] = v;
        }
    }
}

// ---------------- chunked selective scan ----------------
// pass 1: per (b, chunk, d): local scan from h=0 over CL_ steps; emit h_end and per-state dA product.
__global__ __launch_bounds__(256) void k_scan1(const float* __restrict__ dpre, const float* __restrict__ u,
                                               const float* __restrict__ xdbl, const float* __restrict__ Alog,
                                               float* __restrict__ hend, float* __restrict__ P){
    __shared__ float sB[CL_*DS_];
    int g = blockIdx.x*256 + threadIdx.x;        // B*NC*DI = 40960
    int d = g % DI_;
    int c = (g/DI_) % NC_;
    int b = g/(DI_*NC_);
    for (int j=threadIdx.x; j<CL_*DS_; j+=256){
        int t0=j>>4, s=j&15;
        sB[j] = xdbl[((size_t)(b*L_ + c*CL_ + t0))*64 + 32 + s];
    }
    __syncthreads();
    float Aloc[DS_];
    #pragma unroll
    for (int s=0;s<DS_;++s) Aloc[s] = -__expf(Alog[d*DS_+s]);
    float h[DS_], Pl[DS_];
    #pragma unroll
    for (int s=0;s<DS_;++s){ h[s]=0.f; Pl[s]=1.f; }
    size_t rowbase = (size_t)(b*L_ + c*CL_);
    for (int t0=0;t0<CL_;++t0){
        float delta = softplusf_(dpre[(rowbase+t0)*DI_ + d]);
        float ut    = u[(rowbase+t0)*DI_ + d];
        float du    = delta*ut;
        #pragma unroll
        for (int s=0;s<DS_;++s){
            float a = __expf(delta*Aloc[s]);
            h[s]  = fmaf(a, h[s], du*sB[t0*DS_+s]);
            Pl[s] *= a;
        }
    }
    size_t ob = ((size_t)((b*NC_+c)*DI_)+d)*DS_;
    #pragma unroll
    for (int s=0;s<DS_;++s){ hend[ob+s]=h[s]; P[ob+s]=Pl[s]; }
}

// pass 2: tiny sequential combine across chunks -> per-chunk initial state
__global__ __launch_bounds__(256) void k_scan2(const float* __restrict__ hend, const float* __restrict__ P,
                                               float* __restrict__ hstart){
    int g = blockIdx.x*256 + threadIdx.x;        // B*DI*DS = 32768
    int s = g % DS_;
    int d = (g/DS_) % DI_;
    int b = g/(DS_*DI_);
    float h = 0.f;
    for (int c=0;c<NC_;++c){
        size_t idx = ((size_t)((b*NC_+c)*DI_)+d)*DS_ + s;
        hstart[idx] = h;
        h = fmaf(P[idx], h, hend[idx]);
    }
}

// pass 3: rerun chunk with correct initial state; emit gated y
__global__ __launch_bounds__(256) void k_scan3(const float* __restrict__ dpre, const float* __restrict__ u,
                                               const float* __restrict__ xdbl, const float* __restrict__ xz,
                                               const float* __restrict__ Alog, const float* __restrict__ Dsk,
                                               const float* __restrict__ hstart, float* __restrict__ y){
    __shared__ float sB[CL_*DS_], sC[CL_*DS_];
    int g = blockIdx.x*256 + threadIdx.x;
    int d = g % DI_;
    int c = (g/DI_) % NC_;
    int b = g/(DI_*NC_);
    for (int j=threadIdx.x; j<CL_*DS_; j+=256){
        int t0=j>>4, s=j&15;
        size_t rb = ((size_t)(b*L_ + c*CL_ + t0))*64;
        sB[j] = xdbl[rb + 32 + s];
        sC[j] = xdbl[rb + 48 + s];
    }
    __syncthreads();
    float Aloc[DS_];
    #pragma unroll
    for (int s=0;s<DS_;++s) Aloc[s] = -__expf(Alog[d*DS_+s]);
    float h[DS_];
    size_t ib = ((size_t)((b*NC_+c)*DI_)+d)*DS_;
    #pragma unroll
    for (int s=0;s<DS_;++s) h[s] = hstart[ib+s];
    float dsk = Dsk[d];
    size_t rowbase = (size_t)(b*L_ + c*CL_);
    for (int t0=0;t0<CL_;++t0){
        size_t off = (rowbase+t0)*DI_ + d;
        float delta = softplusf_(dpre[off]);
        float ut    = u[off];
        float du    = delta*ut;
        float yt    = 0.f;
        #pragma unroll
        for (int s=0;s<DS_;++s){
            float a = __expf(delta*Aloc[s]);
            h[s] = fmaf(a, h[s], du*sB[t0*DS_+s]);
            yt   = fmaf(h[s], sC[t0*DS_+s], yt);
        }
        float zt = xz[(rowbase+t0)*2048 + DI_ + d];
        y[off] = (yt + ut*dsk) * siluf_(zt);
    }
}

// ---------------- layernorm on target rows only ----------------
__global__ __launch_bounds__(256) void k_ln_tgt(const float* __restrict__ x, const float* __restrict__ g_,
                                                const float* __restrict__ b_, float* __restrict__ xn){
    int r = blockIdx.x;                           // 0..B*TGT-1
    int b = r / TGT_, t = r % TGT_;
    const float* row = x + ((size_t)(b*L_+CTX_+t))*DM_;
    int tid = threadIdx.x;
    float2 v = *(const float2*)&row[tid*2];
    float s = v.x+v.y, sq = v.x*v.x+v.y*v.y;
    #pragma unroll
    for (int off=32; off; off>>=1){ s += __shfl_down(s,off); sq += __shfl_down(sq,off); }
    __shared__ float ss[4], ssq[4];
    int w = tid>>6, ln = tid&63;
    if (ln==0){ ss[w]=s; ssq[w]=sq; }
    __syncthreads();
    if (tid==0){
        float S=ss[0]+ss[1]+ss[2]+ss[3], Q=ssq[0]+ssq[1]+ssq[2]+ssq[3];
        float mu = S/(float)DM_;
        float var = Q/(float)DM_ - mu*mu;
        ss[0]=mu; ssq[0]=rsqrtf(var+1e-5f);
    }
    __syncthreads();
    float mu=ss[0], rs=ssq[0];
    xn[(size_t)r*DM_ + tid*2+0] = (v.x-mu)*rs*g_[tid*2+0] + b_[tid*2+0];
    xn[(size_t)r*DM_ + tid*2+1] = (v.y-mu)*rs*g_[tid*2+1] + b_[tid*2+1];
}

// ---------------- host launch ----------------
extern "C" void kernel_launch(void* const* d_in, const int* in_sizes, int n_in,
                              void* d_out, int out_size, void* d_ws, size_t ws_size,
                              hipStream_t stream) {
    const float* ctx    = (const float*)d_in[0];
    const float* te     = (const float*)d_in[1];
    const float* ve     = (const float*)d_in[2];
    // d_in[3] = target_count (fixed 256), unused
    const float* pos_w  = (const float*)d_in[4];
    const float* pos_b  = (const float*)d_in[5];
    const float* outp_w = (const float*)d_in[6];
    const float* outp_b = (const float*)d_in[7];
    const float* ln_g   = (const float*)d_in[8];
    const float* ln_b   = (const float*)d_in[9];
    const float* in_w   = (const float*)d_in[10];
    const float* conv_w = (const float*)d_in[11];
    const float* conv_b = (const float*)d_in[12];
    const float* xproj_w= (const float*)d_in[13];
    const float* dt_w   = (const float*)d_in[14];
    const float* dt_b   = (const float*)d_in[15];
    const float* A_log  = (const float*)d_in[16];
    const float* D_skip = (const float*)d_in[17];
    const float* out_w  = (const float*)d_in[18];
    float* out = (float*)d_out;

    float* ws   = (float*)d_ws;
    float* x    = ws;                              // 2560*512
    float* tc   = x    + (size_t)MROWS_*DM_;       // 512*1024
    float* pos  = tc   + (size_t)B_*TGT_*2*DM_;    // 512*512
    float* xz   = pos  + (size_t)B_*TGT_*DM_;      // 2560*2048
    float* u    = xz   + (size_t)MROWS_*2048;      // 2560*1024
    float* xdbl = u    + (size_t)MROWS_*DI_;       // 2560*64
    float* dpre = xdbl + (size_t)MROWS_*64;        // 2560*1024
    float* y    = dpre + (size_t)MROWS_*DI_;       // 2560*1024
    float* hend = y    + (size_t)MROWS_*DI_;       // 2*20*1024*16
    float* P    = hend + (size_t)B_*NC_*DI_*DS_;
    float* hst  = P    + (size_t)B_*NC_*DI_*DS_;
    float* xn   = hst  + (size_t)B_*NC_*DI_*DS_;   // 512*512

    k_copy_ctx   <<<4096, 256, 0, stream>>>(ctx, x);
    k_build_tc   <<<2048, 256, 0, stream>>>(te, ve, tc);
    k_mm<false>  <<<dim3(8,8),   256, 0, stream>>>(tc, 2*DM_, pos_w, 2*DM_, pos, DM_, pos_b, 2*DM_);
    k_scatter_pos<<<1024, 256, 0, stream>>>(pos, x);

    for (int i=0;i<NL_;++i){
        const float* inw  = in_w    + (size_t)i*2*DI_*DM_;
        const float* cw   = conv_w  + (size_t)i*DI_*DCONV_;
        const float* cb   = conv_b  + (size_t)i*DI_;
        const float* xpw  = xproj_w + (size_t)i*(DTR_+2*DS_)*DI_;
        const float* dtw  = dt_w    + (size_t)i*DI_*DTR_;
        const float* dtb  = dt_b    + (size_t)i*DI_;
        const float* Ai   = A_log   + (size_t)i*DI_*DS_;
        const float* Dsk  = D_skip  + (size_t)i*DI_;
        const float* outw = out_w   + (size_t)i*DM_*DI_;

        k_mm<false><<<dim3(32,40), 256, 0, stream>>>(x, DM_, inw, DM_, xz, 2*DI_, nullptr, DM_);
        k_conv_silu<<<10240, 256, 0, stream>>>(xz, cw, cb, u);
        k_mm<false><<<dim3(1,40),  256, 0, stream>>>(u, DI_, xpw, DI_, xdbl, 64, nullptr, DI_);
        k_mm<false><<<dim3(16,40), 256, 0, stream>>>(xdbl, 64, dtw, DTR_, dpre, DI_, dtb, DTR_);
        k_scan1<<<160, 256, 0, stream>>>(dpre, u, xdbl, Ai, hend, P);
        k_scan2<<<128, 256, 0, stream>>>(hend, P, hst);
        k_scan3<<<160, 256, 0, stream>>>(dpre, u, xdbl, xz, Ai, Dsk, hst, y);
        k_mm<true> <<<dim3(8,40),  256, 0, stream>>>(y, DI_, outw, DI_, x, DM_, nullptr, DI_);
    }

    k_ln_tgt  <<<512, 256, 0, stream>>>(x, ln_g, ln_b, xn);
    k_mm<false><<<dim3(8,8), 256, 0, stream>>>(xn, DM_, outp_w, DM_, out, DM_, outp_b, DM_);
}

// Round 2
// 435.499 us; speedup vs baseline: 1.8364x; 1.8364x over previous
//
#include <hip/hip_runtime.h>
#include <hip/hip_bf16.h>

// Problem constants (match reference)
#define B_     2
#define CTX_   1024
#define TGT_   256
#define DM_    512
#define L_     1280          // CTX + TGT
#define DI_    1024          // EXPAND * D_MODEL
#define DS_    16            // D_STATE
#define DCONV_ 4
#define NL_    2
#define DTR_   32            // DT_RANK
#define MROWS_ (B_*L_)       // 2560
#define NC_    80            // scan chunks
#define CL_    16            // chunk length (NC_*CL_ == L_)

typedef unsigned short u16;
typedef __attribute__((ext_vector_type(8))) __bf16 bf16x8;
typedef __attribute__((ext_vector_type(4))) float f32x4;

__device__ __forceinline__ float sigmoidf_(float v){ return 1.f/(1.f+__expf(-v)); }
__device__ __forceinline__ float siluf_(float v){ return v*sigmoidf_(v); }
__device__ __forceinline__ float softplusf_(float v){ return (v>20.f)?v:log1pf(__expf(v)); }
__device__ __forceinline__ u16 f2b(float f){
    union { float f; unsigned u; } x; x.f = f;
    unsigned u = x.u;
    return (u16)((u + 0x7fffu + ((u>>16)&1u)) >> 16);
}

// ---------------- small data-movement kernels ----------------

__global__ __launch_bounds__(256) void k_copy_ctx(const float* __restrict__ ctx, float* __restrict__ x){
    int i = blockIdx.x*256 + threadIdx.x;        // B*CTX*DM = 1,048,576
    int d = i % DM_;
    int l = (i/DM_) % CTX_;
    int b = i/(DM_*CTX_);
    x[((size_t)(b*L_+l))*DM_ + d] = ctx[i];
}

// build tc directly in bf16
__global__ __launch_bounds__(256) void k_build_tc(const float* __restrict__ te, const float* __restrict__ ve,
                                                  u16* __restrict__ tcb){
    int i = blockIdx.x*256 + threadIdx.x;        // B*TGT*2DM = 524,288
    int k = i % (2*DM_);
    int r = i / (2*DM_);                          // b*TGT + t
    float v = (k < DM_) ? te[(size_t)r*DM_ + k] : ve[(size_t)r*DM_ + (k-DM_)];
    tcb[i] = f2b(v);
}

__global__ __launch_bounds__(256) void k_scatter_pos(const float* __restrict__ pos, float* __restrict__ x){
    int i = blockIdx.x*256 + threadIdx.x;        // B*TGT*DM = 262,144
    int d = i % DM_;
    int r = i / DM_;                              // b*TGT + t
    int b = r / TGT_, t = r % TGT_;
    x[((size_t)(b*L_+CTX_+t))*DM_ + d] = pos[i];
}

// fp32 -> bf16, 8 elements/thread (n must be multiple of 2048)
__global__ __launch_bounds__(256) void k_f2b(const float* __restrict__ s, u16* __restrict__ d){
    int i = blockIdx.x*256 + threadIdx.x;
    int base = i*8;
    float4 a = *(const float4*)&s[base];
    float4 b = *(const float4*)&s[base+4];
    union { u16 us[8]; uint4 v; } o;
    o.us[0]=f2b(a.x); o.us[1]=f2b(a.y); o.us[2]=f2b(a.z); o.us[3]=f2b(a.w);
    o.us[4]=f2b(b.x); o.us[5]=f2b(b.y); o.us[6]=f2b(b.z); o.us[7]=f2b(b.w);
    *(uint4*)&d[base] = o.v;
}

// depthwise causal conv (kernel 4) + bias + silu;  xc = xz[:, :, 0:1024]
__global__ __launch_bounds__(256) void k_conv_silu(const float* __restrict__ xz, const float* __restrict__ cw,
                                                   const float* __restrict__ cb, float* __restrict__ u){
    int i = blockIdx.x*256 + threadIdx.x;        // MROWS_*DI_ = 2,621,440
    int d = i % DI_;
    int l = (i/DI_) % L_;
    int b = i/(DI_*L_);
    const float* base = xz + (size_t)b*L_*2048 + d;
    float acc = cb[d];
    #pragma unroll
    for (int k=0;k<DCONV_;++k){
        int ll = l-3+k;
        if (ll >= 0) acc = fmaf(base[(size_t)ll*2048], cw[d*DCONV_+k], acc);
    }
    u[i] = siluf_(acc);
}

// ---------------- bf16 MFMA GEMM:  C[M,N] = A[M,K] * W[N,K]^T (+bias)(+C), fp32 out, optional bf16 dual-write ----
// M%128==0, N%128==0, K%32==0. 128x128 tile, 4 waves (2x2), each wave 64x64 = 4x4 mfma_16x16x32 frags.
#define LDST_ 40   // bf16 elems per LDS row (80 B: 16B-aligned, banks spread)
template<bool ACC>
__global__ __launch_bounds__(256) void k_mmx(const u16* __restrict__ A, int lda,
                                             const u16* __restrict__ Bw, int ldb,
                                             float* __restrict__ C, int ldc,
                                             const float* __restrict__ bias, int K,
                                             u16* __restrict__ Cb, int ldcb){
    __shared__ u16 As[128*LDST_];
    __shared__ u16 Bs[128*LDST_];
    int tid = threadIdx.x;
    int wave = tid >> 6, lane = tid & 63;
    int bm = blockIdx.y*128, bn = blockIdx.x*128;
    int wr = (wave>>1)*64, wc = (wave&1)*64;
    f32x4 acc[4][4] = {};
    int lrow = lane & 15, lk = (lane>>4)*8;
    for (int k0 = 0; k0 < K; k0 += 32){
        #pragma unroll
        for (int i=0;i<2;++i){
            int slot = tid + i*256;          // 0..511
            int rr = slot >> 2;              // 0..127
            int cc = (slot & 3) * 8;         // 0,8,16,24
            *(uint4*)&As[rr*LDST_+cc] = *(const uint4*)&A [(size_t)(bm+rr)*lda + k0 + cc];
            *(uint4*)&Bs[rr*LDST_+cc] = *(const uint4*)&Bw[(size_t)(bn+rr)*ldb + k0 + cc];
        }
        __syncthreads();
        bf16x8 af[4], bf[4];
        #pragma unroll
        for (int f=0; f<4; ++f){
            af[f] = *(const bf16x8*)&As[(wr + f*16 + lrow)*LDST_ + lk];
            bf[f] = *(const bf16x8*)&Bs[(wc + f*16 + lrow)*LDST_ + lk];
        }
        #pragma unroll
        for (int fm=0; fm<4; ++fm)
            #pragma unroll
            for (int fn=0; fn<4; ++fn)
                acc[fm][fn] = __builtin_amdgcn_mfma_f32_16x16x32_bf16(af[fm], bf[fn], acc[fm][fn], 0,0,0);
        __syncthreads();
    }
    // C/D layout: col = lane&15, row = (lane>>4)*4 + j
    #pragma unroll
    for (int fm=0; fm<4; ++fm){
        int m0 = bm + wr + fm*16 + (lane>>4)*4;
        #pragma unroll
        for (int fn=0; fn<4; ++fn){
            int n = bn + wc + fn*16 + (lane&15);
            float bsv = bias ? bias[n] : 0.f;
            #pragma unroll
            for (int j=0; j<4; ++j){
                float v = acc[fm][fn][j] + bsv;
                size_t off = (size_t)(m0+j)*ldc + n;
                if (ACC) v += C[off];
                C[off] = v;
                if (Cb) Cb[(size_t)(m0+j)*ldcb + n] = f2b(v);
            }
        }
    }
}

// ---------------- fp32 tiled GEMM 64x64 (used for dpre: K=32) ----------------
template<bool ACC>
__global__ __launch_bounds__(256) void k_mm(const float* __restrict__ A, int lda,
                                            const float* __restrict__ Bw, int ldb,
                                            float* __restrict__ C, int ldc,
                                            const float* __restrict__ bias, int K){
    __shared__ float As[32][68];   // [k][m]
    __shared__ float Bs[32][68];   // [k][n]
    int tid = threadIdx.x;
    int bm = blockIdx.y*64, bn = blockIdx.x*64;
    int tx = tid & 15, ty = tid >> 4;
    float acc[4][4] = {};
    for (int k0 = 0; k0 < K; k0 += 32){
        #pragma unroll
        for (int i=0;i<2;++i){
            int slot = tid + i*256;
            int r  = slot >> 3;
            int kv = (slot & 7) << 2;
            float4 a4 = *(const float4*)&A [(size_t)(bm+r)*lda + k0 + kv];
            As[kv+0][r]=a4.x; As[kv+1][r]=a4.y; As[kv+2][r]=a4.z; As[kv+3][r]=a4.w;
            float4 b4 = *(const float4*)&Bw[(size_t)(bn+r)*ldb + k0 + kv];
            Bs[kv+0][r]=b4.x; Bs[kv+1][r]=b4.y; Bs[kv+2][r]=b4.z; Bs[kv+3][r]=b4.w;
        }
        __syncthreads();
        #pragma unroll
        for (int k=0;k<32;++k){
            float4 av = *(const float4*)&As[k][ty*4];
            float4 bv = *(const float4*)&Bs[k][tx*4];
            float a_[4]={av.x,av.y,av.z,av.w};
            float b_[4]={bv.x,bv.y,bv.z,bv.w};
            #pragma unroll
            for (int ii=0;ii<4;++ii)
                #pragma unroll
                for (int jj=0;jj<4;++jj)
                    acc[ii][jj] = fmaf(a_[ii], b_[jj], acc[ii][jj]);
        }
        __syncthreads();
    }
    #pragma unroll
    for (int ii=0;ii<4;++ii){
        int m = bm + ty*4 + ii;
        #pragma unroll
        for (int jj=0;jj<4;++jj){
            int n = bn + tx*4 + jj;
            float v = acc[ii][jj];
            if (bias) v += bias[n];
            if (ACC)  v += C[(size_t)m*ldc + n];
            C[(size_t)m*ldc + n] = v;
        }
    }
}

// ---------------- fp32 tiled GEMM 32x32 (used for x_dbl: N=64, K=1024 — needs more blocks) ----------------
__global__ __launch_bounds__(256) void k_mm32(const float* __restrict__ A, int lda,
                                              const float* __restrict__ Bw, int ldb,
                                              float* __restrict__ C, int ldc, int K){
    __shared__ float As[32][33], Bs[32][33];   // [k][m] / [k][n]
    int tid = threadIdx.x;
    int bm = blockIdx.y*32, bn = blockIdx.x*32;
    int tx = tid & 15, ty = tid >> 4;
    float acc[2][2] = {};
    for (int k0=0; k0<K; k0+=32){
        int r  = tid >> 3;          // 0..31
        int kv = (tid & 7) * 4;     // 0..28
        float4 a4 = *(const float4*)&A [(size_t)(bm+r)*lda + k0 + kv];
        As[kv+0][r]=a4.x; As[kv+1][r]=a4.y; As[kv+2][r]=a4.z; As[kv+3][r]=a4.w;
        float4 b4 = *(const float4*)&Bw[(size_t)(bn+r)*ldb + k0 + kv];
        Bs[kv+0][r]=b4.x; Bs[kv+1][r]=b4.y; Bs[kv+2][r]=b4.z; Bs[kv+3][r]=b4.w;
        __syncthreads();
        #pragma unroll
        for (int k=0;k<32;++k){
            float a0=As[k][ty*2], a1=As[k][ty*2+1];
            float b0=Bs[k][tx*2], b1=Bs[k][tx*2+1];
            acc[0][0]=fmaf(a0,b0,acc[0][0]); acc[0][1]=fmaf(a0,b1,acc[0][1]);
            acc[1][0]=fmaf(a1,b0,acc[1][0]); acc[1][1]=fmaf(a1,b1,acc[1][1]);
        }
        __syncthreads();
    }
    #pragma unroll
    for (int ii=0;ii<2;++ii)
        #pragma unroll
        for (int jj=0;jj<2;++jj)
            C[(size_t)(bm+ty*2+ii)*ldc + bn+tx*2+jj] = acc[ii][jj];
}

// ---------------- chunked selective scan ----------------
__global__ __launch_bounds__(256) void k_scan1(const float* __restrict__ dpre, const float* __restrict__ u,
                                               const float* __restrict__ xdbl, const float* __restrict__ Alog,
                                               float* __restrict__ hend, float* __restrict__ P){
    __shared__ float sB[CL_*DS_];
    int g = blockIdx.x*256 + threadIdx.x;        // B*NC*DI = 163,840
    int d = g % DI_;
    int c = (g/DI_) % NC_;
    int b = g/(DI_*NC_);
    if (threadIdx.x < CL_*DS_){
        int t0 = threadIdx.x>>4, s = threadIdx.x&15;
        sB[threadIdx.x] = xdbl[((size_t)(b*L_ + c*CL_ + t0))*64 + 32 + s];
    }
    __syncthreads();
    float Aloc[DS_];
    #pragma unroll
    for (int s=0;s<DS_;++s) Aloc[s] = -__expf(Alog[d*DS_+s]);
    float h[DS_], Pl[DS_];
    #pragma unroll
    for (int s=0;s<DS_;++s){ h[s]=0.f; Pl[s]=1.f; }
    size_t rowbase = (size_t)(b*L_ + c*CL_);
    for (int t0=0;t0<CL_;++t0){
        float delta = softplusf_(dpre[(rowbase+t0)*DI_ + d]);
        float ut    = u[(rowbase+t0)*DI_ + d];
        float du    = delta*ut;
        #pragma unroll
        for (int s=0;s<DS_;++s){
            float a = __expf(delta*Aloc[s]);
            h[s]  = fmaf(a, h[s], du*sB[t0*DS_+s]);
            Pl[s] *= a;
        }
    }
    size_t ob = ((size_t)((b*NC_+c)*DI_)+d)*DS_;
    #pragma unroll
    for (int s=0;s<DS_;++s){ hend[ob+s]=h[s]; P[ob+s]=Pl[s]; }
}

// pass 2: sequential combine across chunks; writes hstart IN-PLACE into hend
__global__ __launch_bounds__(256) void k_scan2(float* __restrict__ hend, const float* __restrict__ P){
    int g = blockIdx.x*256 + threadIdx.x;        // B*DI*DS = 32768
    int s = g % DS_;
    int d = (g/DS_) % DI_;
    int b = g/(DS_*DI_);
    float h = 0.f;
    for (int c=0;c<NC_;++c){
        size_t idx = ((size_t)((b*NC_+c)*DI_)+d)*DS_ + s;
        float he = hend[idx], p = P[idx];
        hend[idx] = h;                       // h at chunk start
        h = fmaf(p, h, he);
    }
}

// pass 3: rerun chunk with correct initial state; emit gated y in bf16
__global__ __launch_bounds__(256) void k_scan3(const float* __restrict__ dpre, const float* __restrict__ u,
                                               const float* __restrict__ xdbl, const float* __restrict__ xz,
                                               const float* __restrict__ Alog, const float* __restrict__ Dsk,
                                               const float* __restrict__ hstart, u16* __restrict__ yb){
    __shared__ float sB[CL_*DS_], sC[CL_*DS_];
    int g = blockIdx.x*256 + threadIdx.x;
    int d = g % DI_;
    int c = (g/DI_) % NC_;
    int b = g/(DI_*NC_);
    if (threadIdx.x < CL_*DS_){
        int t0 = threadIdx.x>>4, s = threadIdx.x&15;
        size_t rb = ((size_t)(b*L_ + c*CL_ + t0))*64;
        sB[threadIdx.x] = xdbl[rb + 32 + s];
        sC[threadIdx.x] = xdbl[rb + 48 + s];
    }
    __syncthreads();
    float Aloc[DS_];
    #pragma unroll
    for (int s=0;s<DS_;++s) Aloc[s] = -__expf(Alog[d*DS_+s]);
    float h[DS_];
    size_t ib = ((size_t)((b*NC_+c)*DI_)+d)*DS_;
    #pragma unroll
    for (int s=0;s<DS_;++s) h[s] = hstart[ib+s];
    float dsk = Dsk[d];
    size_t rowbase = (size_t)(b*L_ + c*CL_);
    for (int t0=0;t0<CL_;++t0){
        size_t off = (rowbase+t0)*DI_ + d;
        float delta = softplusf_(dpre[off]);
        float ut    = u[off];
        float du    = delta*ut;
        float yt    = 0.f;
        #pragma unroll
        for (int s=0;s<DS_;++s){
            float a = __expf(delta*Aloc[s]);
            h[s] = fmaf(a, h[s], du*sB[t0*DS_+s]);
            yt   = fmaf(h[s], sC[t0*DS_+s], yt);
        }
        float zt = xz[(rowbase+t0)*2048 + DI_ + d];
        yb[off] = f2b((yt + ut*dsk) * siluf_(zt));
    }
}

// ---------------- layernorm on target rows only, bf16 out ----------------
__global__ __launch_bounds__(256) void k_ln_tgt(const float* __restrict__ x, const float* __restrict__ g_,
                                                const float* __restrict__ b_, u16* __restrict__ xnb){
    int r = blockIdx.x;                           // 0..B*TGT-1
    int b = r / TGT_, t = r % TGT_;
    const float* row = x + ((size_t)(b*L_+CTX_+t))*DM_;
    int tid = threadIdx.x;
    float2 v = *(const float2*)&row[tid*2];
    float s = v.x+v.y, sq = v.x*v.x+v.y*v.y;
    #pragma unroll
    for (int off=32; off; off>>=1){ s += __shfl_down(s,off); sq += __shfl_down(sq,off); }
    __shared__ float ss[4], ssq[4];
    int w = tid>>6, ln = tid&63;
    if (ln==0){ ss[w]=s; ssq[w]=sq; }
    __syncthreads();
    if (tid==0){
        float S=ss[0]+ss[1]+ss[2]+ss[3], Q=ssq[0]+ssq[1]+ssq[2]+ssq[3];
        float mu = S/(float)DM_;
        float var = Q/(float)DM_ - mu*mu;
        ss[0]=mu; ssq[0]=rsqrtf(var+1e-5f);
    }
    __syncthreads();
    float mu=ss[0], rs=ssq[0];
    xnb[(size_t)r*DM_ + tid*2+0] = f2b((v.x-mu)*rs*g_[tid*2+0] + b_[tid*2+0]);
    xnb[(size_t)r*DM_ + tid*2+1] = f2b((v.y-mu)*rs*g_[tid*2+1] + b_[tid*2+1]);
}

// ---------------- host launch ----------------
extern "C" void kernel_launch(void* const* d_in, const int* in_sizes, int n_in,
                              void* d_out, int out_size, void* d_ws, size_t ws_size,
                              hipStream_t stream) {
    const float* ctx    = (const float*)d_in[0];
    const float* te     = (const float*)d_in[1];
    const float* ve     = (const float*)d_in[2];
    const float* pos_w  = (const float*)d_in[4];
    const float* pos_b  = (const float*)d_in[5];
    const float* outp_w = (const float*)d_in[6];
    const float* outp_b = (const float*)d_in[7];
    const float* ln_g   = (const float*)d_in[8];
    const float* ln_b   = (const float*)d_in[9];
    const float* in_w   = (const float*)d_in[10];
    const float* conv_w = (const float*)d_in[11];
    const float* conv_b = (const float*)d_in[12];
    const float* xproj_w= (const float*)d_in[13];
    const float* dt_w   = (const float*)d_in[14];
    const float* dt_b   = (const float*)d_in[15];
    const float* A_log  = (const float*)d_in[16];
    const float* D_skip = (const float*)d_in[17];
    const float* out_w  = (const float*)d_in[18];
    float* out = (float*)d_out;

    float* ws   = (float*)d_ws;
    float* x    = ws;                       // 1,310,720
    float* xz   = x    + 1310720;           // 5,242,880
    float* u    = xz   + 5242880;           // 2,621,440
    float* xdbl = u    + 2621440;           //   163,840
    float* dpre = xdbl + 163840;            // 2,621,440
    float* pos  = dpre + 2621440;           //   262,144
    float* hend = pos  + 262144;            // 2,621,440  (B*NC*DI*DS)
    float* P    = hend + 2621440;           // 2,621,440
    u16*  xb    = (u16*)(P + 2621440);      // 1,310,720 u16
    u16*  tcb   = xb    + 1310720;          //   524,288
    u16*  yb    = tcb   + 524288;           // 2,621,440
    u16*  xnb   = yb    + 2621440;          //   262,144
    u16*  inwb  = xnb   + 262144;           // 2,097,152
    u16*  outwb = inwb  + 2097152;          // 1,048,576
    u16*  poswb = outwb + 1048576;          //   524,288
    u16*  outpwb= poswb + 524288;           //   262,144

    // weight conversions (bf16)
    k_f2b<<<1024, 256, 0, stream>>>(in_w,   inwb);
    k_f2b<<< 512, 256, 0, stream>>>(out_w,  outwb);
    k_f2b<<< 256, 256, 0, stream>>>(pos_w,  poswb);
    k_f2b<<< 128, 256, 0, stream>>>(outp_w, outpwb);

    k_copy_ctx   <<<4096, 256, 0, stream>>>(ctx, x);
    k_build_tc   <<<2048, 256, 0, stream>>>(te, ve, tcb);
    k_mmx<false> <<<dim3(4,4), 256, 0, stream>>>(tcb, 2*DM_, poswb, 2*DM_, pos, DM_, pos_b, 2*DM_, nullptr, 0);
    k_scatter_pos<<<1024, 256, 0, stream>>>(pos, x);
    k_f2b        <<< 640, 256, 0, stream>>>(x, xb);

    for (int i=0;i<NL_;++i){
        const u16*   inwbi = inwb  + (size_t)i*2*DI_*DM_;
        const float* cw    = conv_w  + (size_t)i*DI_*DCONV_;
        const float* cb    = conv_b  + (size_t)i*DI_;
        const float* xpw   = xproj_w + (size_t)i*(DTR_+2*DS_)*DI_;
        const float* dtw   = dt_w    + (size_t)i*DI_*DTR_;
        const float* dtb   = dt_b    + (size_t)i*DI_;
        const float* Ai    = A_log   + (size_t)i*DI_*DS_;
        const float* Dsk   = D_skip  + (size_t)i*DI_;
        const u16*   outwbi= outwb + (size_t)i*DM_*DI_;

        k_mmx<false><<<dim3(16,20), 256, 0, stream>>>(xb, DM_, inwbi, DM_, xz, 2*DI_, nullptr, DM_, nullptr, 0);
        k_conv_silu <<<10240, 256, 0, stream>>>(xz, cw, cb, u);
        k_mm32      <<<dim3(2,80),  256, 0, stream>>>(u, DI_, xpw, DI_, xdbl, 64, DI_);
        k_mm<false> <<<dim3(16,40), 256, 0, stream>>>(xdbl, 64, dtw, DTR_, dpre, DI_, dtb, DTR_);
        k_scan1<<<640, 256, 0, stream>>>(dpre, u, xdbl, Ai, hend, P);
        k_scan2<<<128, 256, 0, stream>>>(hend, P);
        k_scan3<<<640, 256, 0, stream>>>(dpre, u, xdbl, xz, Ai, Dsk, hend, yb);
        // out-proj: accumulate into x (fp32) and dual-write bf16 xb for next layer
        k_mmx<true> <<<dim3(4,20),  256, 0, stream>>>(yb, DI_, outwbi, DI_, x, DM_, nullptr, DI_, xb, DM_);
    }

    k_ln_tgt    <<<512, 256, 0, stream>>>(x, ln_g, ln_b, xnb);
    k_mmx<false><<<dim3(4,4), 256, 0, stream>>>(xnb, DM_, outpwb, DM_, out, DM_, outp_b, DM_, nullptr, 0);
}

// Round 3
// 302.759 us; speedup vs baseline: 2.6415x; 1.4384x over previous
//
#include <hip/hip_runtime.h>
#include <hip/hip_bf16.h>

// Problem constants (match reference)
#define B_     2
#define CTX_   1024
#define TGT_   256
#define DM_    512
#define L_     1280          // CTX + TGT
#define DI_    1024          // EXPAND * D_MODEL
#define DS_    16            // D_STATE
#define DCONV_ 4
#define NL_    2
#define DTR_   32            // DT_RANK
#define MROWS_ (B_*L_)       // 2560
#define NC_    80            // scan chunks
#define CL_    16            // chunk length (NC_*CL_ == L_)
#define XDBL_N_ (MROWS_*64)  // 163840

typedef unsigned short u16;
typedef __attribute__((ext_vector_type(8))) __bf16 bf16x8;
typedef __attribute__((ext_vector_type(4))) float f32x4;

__device__ __forceinline__ float sigmoidf_(float v){ return 1.f/(1.f+__expf(-v)); }
__device__ __forceinline__ float siluf_(float v){ return v*sigmoidf_(v); }
__device__ __forceinline__ float softplusf_(float v){ return (v>20.f)?v:log1pf(__expf(v)); }
__device__ __forceinline__ u16 f2b(float f){
    union { float f; unsigned u; } x; x.f = f;
    unsigned u = x.u;
    return (u16)((u + 0x7fffu + ((u>>16)&1u)) >> 16);
}

// ---------------- small data-movement kernels ----------------

__global__ __launch_bounds__(256) void k_copy_ctx(const float* __restrict__ ctx, float* __restrict__ x,
                                                  u16* __restrict__ xb){
    int i = blockIdx.x*256 + threadIdx.x;        // B*CTX*DM = 1,048,576
    int d = i % DM_;
    int l = (i/DM_) % CTX_;
    int b = i/(DM_*CTX_);
    float v = ctx[i];
    size_t o = ((size_t)(b*L_+l))*DM_ + d;
    x[o] = v; xb[o] = f2b(v);
}

__global__ __launch_bounds__(256) void k_build_tc(const float* __restrict__ te, const float* __restrict__ ve,
                                                  u16* __restrict__ tcb){
    int i = blockIdx.x*256 + threadIdx.x;        // B*TGT*2DM = 524,288
    int k = i % (2*DM_);
    int r = i / (2*DM_);
    float v = (k < DM_) ? te[(size_t)r*DM_ + k] : ve[(size_t)r*DM_ + (k-DM_)];
    tcb[i] = f2b(v);
}

__global__ __launch_bounds__(256) void k_scatter_pos(const float* __restrict__ pos, float* __restrict__ x,
                                                     u16* __restrict__ xb){
    int i = blockIdx.x*256 + threadIdx.x;        // B*TGT*DM = 262,144
    int d = i % DM_;
    int r = i / DM_;
    int b = r / TGT_, t = r % TGT_;
    float v = pos[i];
    size_t o = ((size_t)(b*L_+CTX_+t))*DM_ + d;
    x[o] = v; xb[o] = f2b(v);
}

// fp32 -> bf16, 8 elements/thread (n must be multiple of 2048)
__global__ __launch_bounds__(256) void k_f2b(const float* __restrict__ s, u16* __restrict__ d){
    int i = blockIdx.x*256 + threadIdx.x;
    int base = i*8;
    float4 a = *(const float4*)&s[base];
    float4 b = *(const float4*)&s[base+4];
    union { u16 us[8]; uint4 v; } o;
    o.us[0]=f2b(a.x); o.us[1]=f2b(a.y); o.us[2]=f2b(a.z); o.us[3]=f2b(a.w);
    o.us[4]=f2b(b.x); o.us[5]=f2b(b.y); o.us[6]=f2b(b.z); o.us[7]=f2b(b.w);
    *(uint4*)&d[base] = o.v;
}

// depthwise causal conv (kernel 4) + bias + silu; dual-write fp32 + bf16
__global__ __launch_bounds__(256) void k_conv_silu(const float* __restrict__ xz, const float* __restrict__ cw,
                                                   const float* __restrict__ cb, float* __restrict__ u,
                                                   u16* __restrict__ ub){
    int i = blockIdx.x*256 + threadIdx.x;        // MROWS_*DI_ = 2,621,440
    int d = i % DI_;
    int l = (i/DI_) % L_;
    int b = i/(DI_*L_);
    const float* base = xz + (size_t)b*L_*2048 + d;
    float acc = cb[d];
    #pragma unroll
    for (int k=0;k<DCONV_;++k){
        int ll = l-3+k;
        if (ll >= 0) acc = fmaf(base[(size_t)ll*2048], cw[d*DCONV_+k], acc);
    }
    float v = siluf_(acc);
    u[i] = v; ub[i] = f2b(v);
}

// ---------------- bf16 MFMA GEMM, 64x64 tile, 4 waves (2x2), each wave 32x32 = 2x2 frags ----
// C[M,N] = A[M,K] * W[N,K]^T (+bias)(+C). M%64==0, N%64==0, K%32==0.
// SPLIT: grid.x = k-split index; each block computes `ksteps` K-steps starting at
// blockIdx.x*ksteps*32 and stores its partial tile to C + blockIdx.x*splitStride (bn=0).
#define LDST_ 40   // bf16 elems per LDS row (80 B)
template<bool ACC, bool SPLIT>
__global__ __launch_bounds__(256) void k_mmx64(const u16* __restrict__ A, int lda,
                                               const u16* __restrict__ Bw, int ldb,
                                               float* __restrict__ C, int ldc,
                                               const float* __restrict__ bias, int ksteps,
                                               u16* __restrict__ Cb, int ldcb, int splitStride){
    __shared__ u16 As[64*LDST_];
    __shared__ u16 Bs[64*LDST_];
    int tid = threadIdx.x;
    int wave = tid >> 6, lane = tid & 63;
    int bm = blockIdx.y*64;
    int bn   = SPLIT ? 0 : blockIdx.x*64;
    int kbase= SPLIT ? blockIdx.x*ksteps*32 : 0;
    int wr = (wave>>1)*32, wc = (wave&1)*32;
    f32x4 acc[2][2] = {};
    int lrow = lane & 15, lk = (lane>>4)*8;
    int rr = tid >> 2, cc = (tid & 3) * 8;
    for (int s = 0; s < ksteps; ++s){
        int k0 = kbase + s*32;
        *(uint4*)&As[rr*LDST_+cc] = *(const uint4*)&A [(size_t)(bm+rr)*lda + k0 + cc];
        *(uint4*)&Bs[rr*LDST_+cc] = *(const uint4*)&Bw[(size_t)(bn+rr)*ldb + k0 + cc];
        __syncthreads();
        bf16x8 af[2], bfr[2];
        #pragma unroll
        for (int f=0; f<2; ++f){
            af [f] = *(const bf16x8*)&As[(wr + f*16 + lrow)*LDST_ + lk];
            bfr[f] = *(const bf16x8*)&Bs[(wc + f*16 + lrow)*LDST_ + lk];
        }
        #pragma unroll
        for (int fm=0; fm<2; ++fm)
            #pragma unroll
            for (int fn=0; fn<2; ++fn)
                acc[fm][fn] = __builtin_amdgcn_mfma_f32_16x16x32_bf16(af[fm], bfr[fn], acc[fm][fn], 0,0,0);
        __syncthreads();
    }
    // C/D layout: col = lane&15, row = (lane>>4)*4 + j
    float* Cout = SPLIT ? (C + (size_t)blockIdx.x*splitStride) : C;
    #pragma unroll
    for (int fm=0; fm<2; ++fm){
        int m0 = bm + wr + fm*16 + (lane>>4)*4;
        #pragma unroll
        for (int fn=0; fn<2; ++fn){
            int n = bn + wc + fn*16 + (lane&15);
            float bsv = (!SPLIT && bias) ? bias[n] : 0.f;
            #pragma unroll
            for (int j=0; j<4; ++j){
                float v = acc[fm][fn][j] + bsv;
                size_t off = (size_t)(m0+j)*ldc + n;
                if (ACC) v += Cout[off];
                Cout[off] = v;
                if (!SPLIT && Cb) Cb[(size_t)(m0+j)*ldcb + n] = f2b(v);
            }
        }
    }
}

// reduce 8 split partials
__global__ __launch_bounds__(256) void k_red8(const float* __restrict__ part, float* __restrict__ out){
    int j = (blockIdx.x*256 + threadIdx.x)*4;    // XDBL_N_/4 threads
    float4 s = *(const float4*)&part[j];
    #pragma unroll
    for (int p=1;p<8;++p){
        float4 t = *(const float4*)&part[(size_t)p*XDBL_N_ + j];
        s.x+=t.x; s.y+=t.y; s.z+=t.z; s.w+=t.w;
    }
    *(float4*)&out[j] = s;
}

// ---------------- fp32 tiled GEMM 64x64 (dpre: K=32), optional softplus epilogue ----------------
template<bool ACC, bool SP>
__global__ __launch_bounds__(256) void k_mm(const float* __restrict__ A, int lda,
                                            const float* __restrict__ Bw, int ldb,
                                            float* __restrict__ C, int ldc,
                                            const float* __restrict__ bias, int K){
    __shared__ float As[32][68];
    __shared__ float Bs[32][68];
    int tid = threadIdx.x;
    int bm = blockIdx.y*64, bn = blockIdx.x*64;
    int tx = tid & 15, ty = tid >> 4;
    float acc[4][4] = {};
    for (int k0 = 0; k0 < K; k0 += 32){
        #pragma unroll
        for (int i=0;i<2;++i){
            int slot = tid + i*256;
            int r  = slot >> 3;
            int kv = (slot & 7) << 2;
            float4 a4 = *(const float4*)&A [(size_t)(bm+r)*lda + k0 + kv];
            As[kv+0][r]=a4.x; As[kv+1][r]=a4.y; As[kv+2][r]=a4.z; As[kv+3][r]=a4.w;
            float4 b4 = *(const float4*)&Bw[(size_t)(bn+r)*ldb + k0 + kv];
            Bs[kv+0][r]=b4.x; Bs[kv+1][r]=b4.y; Bs[kv+2][r]=b4.z; Bs[kv+3][r]=b4.w;
        }
        __syncthreads();
        #pragma unroll
        for (int k=0;k<32;++k){
            float4 av = *(const float4*)&As[k][ty*4];
            float4 bv = *(const float4*)&Bs[k][tx*4];
            float a_[4]={av.x,av.y,av.z,av.w};
            float b_[4]={bv.x,bv.y,bv.z,bv.w};
            #pragma unroll
            for (int ii=0;ii<4;++ii)
                #pragma unroll
                for (int jj=0;jj<4;++jj)
                    acc[ii][jj] = fmaf(a_[ii], b_[jj], acc[ii][jj]);
        }
        __syncthreads();
    }
    #pragma unroll
    for (int ii=0;ii<4;++ii){
        int m = bm + ty*4 + ii;
        #pragma unroll
        for (int jj=0;jj<4;++jj){
            int n = bn + tx*4 + jj;
            float v = acc[ii][jj];
            if (bias) v += bias[n];
            if (ACC)  v += C[(size_t)m*ldc + n];
            if (SP)   v  = softplusf_(v);
            C[(size_t)m*ldc + n] = v;
        }
    }
}

// ---------------- chunked selective scan (dpre already softplus'ed) ----------------
__global__ __launch_bounds__(256) void k_scan1(const float* __restrict__ dpre, const float* __restrict__ u,
                                               const float* __restrict__ xdbl, const float* __restrict__ Alog,
                                               float* __restrict__ hend, float* __restrict__ P){
    __shared__ float sB[CL_*DS_];
    int g = blockIdx.x*256 + threadIdx.x;        // B*NC*DI = 163,840
    int d = g % DI_;
    int c = (g/DI_) % NC_;
    int b = g/(DI_*NC_);
    if (threadIdx.x < CL_*DS_){
        int t0 = threadIdx.x>>4, s = threadIdx.x&15;
        sB[threadIdx.x] = xdbl[((size_t)(b*L_ + c*CL_ + t0))*64 + 32 + s];
    }
    __syncthreads();
    float Aloc[DS_];
    #pragma unroll
    for (int s=0;s<DS_;++s) Aloc[s] = -__expf(Alog[d*DS_+s]);
    float h[DS_], Pl[DS_];
    #pragma unroll
    for (int s=0;s<DS_;++s){ h[s]=0.f; Pl[s]=1.f; }
    size_t rowbase = (size_t)(b*L_ + c*CL_);
    for (int t0=0;t0<CL_;++t0){
        float delta = dpre[(rowbase+t0)*DI_ + d];
        float ut    = u[(rowbase+t0)*DI_ + d];
        float du    = delta*ut;
        #pragma unroll
        for (int s=0;s<DS_;++s){
            float a = __expf(delta*Aloc[s]);
            h[s]  = fmaf(a, h[s], du*sB[t0*DS_+s]);
            Pl[s] *= a;
        }
    }
    size_t ob = ((size_t)((b*NC_+c)*DI_)+d)*DS_;
    #pragma unroll
    for (int s=0;s<DS_;++s){ hend[ob+s]=h[s]; P[ob+s]=Pl[s]; }
}

// pass 2: sequential combine across chunks; writes hstart IN-PLACE into hend
__global__ __launch_bounds__(256) void k_scan2(float* __restrict__ hend, const float* __restrict__ P){
    int g = blockIdx.x*256 + threadIdx.x;        // B*DI*DS = 32768
    int s = g % DS_;
    int d = (g/DS_) % DI_;
    int b = g/(DS_*DI_);
    float h = 0.f;
    for (int c=0;c<NC_;++c){
        size_t idx = ((size_t)((b*NC_+c)*DI_)+d)*DS_ + s;
        float he = hend[idx], p = P[idx];
        hend[idx] = h;
        h = fmaf(p, h, he);
    }
}

// pass 3: rerun chunk with correct initial state; emit gated y in bf16
__global__ __launch_bounds__(256) void k_scan3(const float* __restrict__ dpre, const float* __restrict__ u,
                                               const float* __restrict__ xdbl, const float* __restrict__ xz,
                                               const float* __restrict__ Alog, const float* __restrict__ Dsk,
                                               const float* __restrict__ hstart, u16* __restrict__ yb){
    __shared__ float sB[CL_*DS_], sC[CL_*DS_];
    int g = blockIdx.x*256 + threadIdx.x;
    int d = g % DI_;
    int c = (g/DI_) % NC_;
    int b = g/(DI_*NC_);
    if (threadIdx.x < CL_*DS_){
        int t0 = threadIdx.x>>4, s = threadIdx.x&15;
        size_t rb = ((size_t)(b*L_ + c*CL_ + t0))*64;
        sB[threadIdx.x] = xdbl[rb + 32 + s];
        sC[threadIdx.x] = xdbl[rb + 48 + s];
    }
    __syncthreads();
    float Aloc[DS_];
    #pragma unroll
    for (int s=0;s<DS_;++s) Aloc[s] = -__expf(Alog[d*DS_+s]);
    float h[DS_];
    size_t ib = ((size_t)((b*NC_+c)*DI_)+d)*DS_;
    #pragma unroll
    for (int s=0;s<DS_;++s) h[s] = hstart[ib+s];
    float dsk = Dsk[d];
    size_t rowbase = (size_t)(b*L_ + c*CL_);
    for (int t0=0;t0<CL_;++t0){
        size_t off = (rowbase+t0)*DI_ + d;
        float delta = dpre[off];
        float ut    = u[off];
        float du    = delta*ut;
        float yt    = 0.f;
        #pragma unroll
        for (int s=0;s<DS_;++s){
            float a = __expf(delta*Aloc[s]);
            h[s] = fmaf(a, h[s], du*sB[t0*DS_+s]);
            yt   = fmaf(h[s], sC[t0*DS_+s], yt);
        }
        float zt = xz[(rowbase+t0)*2048 + DI_ + d];
        yb[off] = f2b((yt + ut*dsk) * siluf_(zt));
    }
}

// ---------------- layernorm on target rows only, bf16 out ----------------
__global__ __launch_bounds__(256) void k_ln_tgt(const float* __restrict__ x, const float* __restrict__ g_,
                                                const float* __restrict__ b_, u16* __restrict__ xnb){
    int r = blockIdx.x;                           // 0..B*TGT-1
    int b = r / TGT_, t = r % TGT_;
    const float* row = x + ((size_t)(b*L_+CTX_+t))*DM_;
    int tid = threadIdx.x;
    float2 v = *(const float2*)&row[tid*2];
    float s = v.x+v.y, sq = v.x*v.x+v.y*v.y;
    #pragma unroll
    for (int off=32; off; off>>=1){ s += __shfl_down(s,off); sq += __shfl_down(sq,off); }
    __shared__ float ss[4], ssq[4];
    int w = tid>>6, ln = tid&63;
    if (ln==0){ ss[w]=s; ssq[w]=sq; }
    __syncthreads();
    if (tid==0){
        float S=ss[0]+ss[1]+ss[2]+ss[3], Q=ssq[0]+ssq[1]+ssq[2]+ssq[3];
        float mu = S/(float)DM_;
        float var = Q/(float)DM_ - mu*mu;
        ss[0]=mu; ssq[0]=rsqrtf(var+1e-5f);
    }
    __syncthreads();
    float mu=ss[0], rs=ssq[0];
    xnb[(size_t)r*DM_ + tid*2+0] = f2b((v.x-mu)*rs*g_[tid*2+0] + b_[tid*2+0]);
    xnb[(size_t)r*DM_ + tid*2+1] = f2b((v.y-mu)*rs*g_[tid*2+1] + b_[tid*2+1]);
}

// ---------------- host launch ----------------
extern "C" void kernel_launch(void* const* d_in, const int* in_sizes, int n_in,
                              void* d_out, int out_size, void* d_ws, size_t ws_size,
                              hipStream_t stream) {
    const float* ctx    = (const float*)d_in[0];
    const float* te     = (const float*)d_in[1];
    const float* ve     = (const float*)d_in[2];
    const float* pos_w  = (const float*)d_in[4];
    const float* pos_b  = (const float*)d_in[5];
    const float* outp_w = (const float*)d_in[6];
    const float* outp_b = (const float*)d_in[7];
    const float* ln_g   = (const float*)d_in[8];
    const float* ln_b   = (const float*)d_in[9];
    const float* in_w   = (const float*)d_in[10];
    const float* conv_w = (const float*)d_in[11];
    const float* conv_b = (const float*)d_in[12];
    const float* xproj_w= (const float*)d_in[13];
    const float* dt_w   = (const float*)d_in[14];
    const float* dt_b   = (const float*)d_in[15];
    const float* A_log  = (const float*)d_in[16];
    const float* D_skip = (const float*)d_in[17];
    const float* out_w  = (const float*)d_in[18];
    float* out = (float*)d_out;

    float* ws    = (float*)d_ws;
    float* x     = ws;                       // 1,310,720
    float* xz    = x     + 1310720;          // 5,242,880
    float* u     = xz    + 5242880;          // 2,621,440
    float* xdbl  = u     + 2621440;          //   163,840
    float* dpre  = xdbl  + 163840;           // 2,621,440
    float* pos   = dpre  + 2621440;          //   262,144
    float* hend  = pos   + 262144;           // 2,621,440
    float* P     = hend  + 2621440;          // 2,621,440
    float* xdblp = P     + 2621440;          // 1,310,720 (8 split partials)
    u16*  xb    = (u16*)(xdblp + 1310720);   // 1,310,720 u16
    u16*  tcb   = xb    + 1310720;           //   524,288
    u16*  yb    = tcb   + 524288;            // 2,621,440
    u16*  xnb   = yb    + 2621440;           //   262,144
    u16*  ub    = xnb   + 262144;            // 2,621,440
    u16*  inwb  = ub    + 2621440;           // 2,097,152
    u16*  outwb = inwb  + 2097152;           // 1,048,576
    u16*  poswb = outwb + 1048576;           //   524,288
    u16*  outpwb= poswb + 524288;            //   262,144
    u16*  xpwb  = outpwb+ 262144;            //   131,072

    // weight conversions (bf16)
    k_f2b<<<1024, 256, 0, stream>>>(in_w,    inwb);
    k_f2b<<< 512, 256, 0, stream>>>(out_w,   outwb);
    k_f2b<<< 256, 256, 0, stream>>>(pos_w,   poswb);
    k_f2b<<< 128, 256, 0, stream>>>(outp_w,  outpwb);
    k_f2b<<<  64, 256, 0, stream>>>(xproj_w, xpwb);

    k_copy_ctx   <<<4096, 256, 0, stream>>>(ctx, x, xb);
    k_build_tc   <<<2048, 256, 0, stream>>>(te, ve, tcb);
    k_mmx64<false,false><<<dim3(8,8), 256, 0, stream>>>(tcb, 2*DM_, poswb, 2*DM_, pos, DM_, pos_b, 32, nullptr, 0, 0);
    k_scatter_pos<<<1024, 256, 0, stream>>>(pos, x, xb);

    for (int i=0;i<NL_;++i){
        const u16*   inwbi  = inwb + (size_t)i*2*DI_*DM_;
        const float* cw     = conv_w  + (size_t)i*DI_*DCONV_;
        const float* cb     = conv_b  + (size_t)i*DI_;
        const u16*   xpwbi  = xpwb + (size_t)i*(DTR_+2*DS_)*DI_;
        const float* dtw    = dt_w    + (size_t)i*DI_*DTR_;
        const float* dtb    = dt_b    + (size_t)i*DI_;
        const float* Ai     = A_log   + (size_t)i*DI_*DS_;
        const float* Dsk    = D_skip  + (size_t)i*DI_;
        const u16*   outwbi = outwb + (size_t)i*DM_*DI_;

        k_mmx64<false,false><<<dim3(32,40), 256, 0, stream>>>(xb, DM_, inwbi, DM_, xz, 2*DI_, nullptr, 16, nullptr, 0, 0);
        k_conv_silu <<<10240, 256, 0, stream>>>(xz, cw, cb, u, ub);
        k_mmx64<false,true><<<dim3(8,40), 256, 0, stream>>>(ub, DI_, xpwbi, DI_, xdblp, 64, nullptr, 4, nullptr, 0, XDBL_N_);
        k_red8      <<<160, 256, 0, stream>>>(xdblp, xdbl);
        k_mm<false,true><<<dim3(16,40), 256, 0, stream>>>(xdbl, 64, dtw, DTR_, dpre, DI_, dtb, DTR_);
        k_scan1<<<640, 256, 0, stream>>>(dpre, u, xdbl, Ai, hend, P);
        k_scan2<<<128, 256, 0, stream>>>(hend, P);
        k_scan3<<<640, 256, 0, stream>>>(dpre, u, xdbl, xz, Ai, Dsk, hend, yb);
        k_mmx64<true,false><<<dim3(8,40), 256, 0, stream>>>(yb, DI_, outwbi, DI_, x, DM_, nullptr, 32, xb, DM_, 0);
    }

    k_ln_tgt<<<512, 256, 0, stream>>>(x, ln_g, ln_b, xnb);
    k_mmx64<false,false><<<dim3(8,8), 256, 0, stream>>>(xnb, DM_, outpwb, DM_, out, DM_, outp_b, 16, nullptr, 0, 0);
}

// Round 4
// 277.551 us; speedup vs baseline: 2.8814x; 1.0908x over previous
//
#include <hip/hip_runtime.h>
#include <hip/hip_bf16.h>

// Problem constants (match reference)
#define B_     2
#define CTX_   1024
#define TGT_   256
#define DM_    512
#define L_     1280          // CTX + TGT
#define DI_    1024          // EXPAND * D_MODEL
#define DS_    16            // D_STATE
#define DCONV_ 4
#define NL_    2
#define DTR_   32            // DT_RANK
#define MROWS_ (B_*L_)       // 2560
#define NC_    80            // scan chunks
#define CL_    16            // chunk length (NC_*CL_ == L_)
#define XDBL_N_ (MROWS_*64)  // 163840

typedef unsigned short u16;
typedef __attribute__((ext_vector_type(8))) __bf16 bf16x8;
typedef __attribute__((ext_vector_type(4))) float f32x4;

__device__ __forceinline__ float sigmoidf_(float v){ return 1.f/(1.f+__expf(-v)); }
__device__ __forceinline__ float siluf_(float v){ return v*sigmoidf_(v); }
__device__ __forceinline__ float softplusf_(float v){ return (v>20.f)?v:log1pf(__expf(v)); }
__device__ __forceinline__ u16 f2b(float f){
    union { float f; unsigned u; } x; x.f = f;
    unsigned u = x.u;
    return (u16)((u + 0x7fffu + ((u>>16)&1u)) >> 16);
}
__device__ __forceinline__ float b2f(u16 v){ return __uint_as_float(((unsigned)v)<<16); }

// ---------------- small data-movement kernels (4 elems/thread) ----------------

__global__ __launch_bounds__(256) void k_copy_ctx(const float* __restrict__ ctx, float* __restrict__ x,
                                                  u16* __restrict__ xb){
    int e = (blockIdx.x*256 + threadIdx.x)*4;    // B*CTX*DM = 1,048,576
    int d = e % DM_;
    int l = (e/DM_) % CTX_;
    int b = e/(DM_*CTX_);
    float4 v = *(const float4*)&ctx[e];
    size_t o = ((size_t)(b*L_+l))*DM_ + d;
    *(float4*)&x[o] = v;
    union { u16 us[4]; uint2 q; } p;
    p.us[0]=f2b(v.x); p.us[1]=f2b(v.y); p.us[2]=f2b(v.z); p.us[3]=f2b(v.w);
    *(uint2*)&xb[o] = p.q;
}

__global__ __launch_bounds__(256) void k_build_tc(const float* __restrict__ te, const float* __restrict__ ve,
                                                  u16* __restrict__ tcb){
    int e = (blockIdx.x*256 + threadIdx.x)*4;    // B*TGT*2DM = 524,288
    int k = e % (2*DM_);
    int r = e / (2*DM_);
    float4 v = (k < DM_) ? *(const float4*)&te[(size_t)r*DM_ + k]
                         : *(const float4*)&ve[(size_t)r*DM_ + (k-DM_)];
    union { u16 us[4]; uint2 q; } p;
    p.us[0]=f2b(v.x); p.us[1]=f2b(v.y); p.us[2]=f2b(v.z); p.us[3]=f2b(v.w);
    *(uint2*)&tcb[e] = p.q;
}

__global__ __launch_bounds__(256) void k_scatter_pos(const float* __restrict__ pos, float* __restrict__ x,
                                                     u16* __restrict__ xb){
    int e = (blockIdx.x*256 + threadIdx.x)*4;    // B*TGT*DM = 262,144
    int d = e % DM_;
    int r = e / DM_;
    int b = r / TGT_, t = r % TGT_;
    float4 v = *(const float4*)&pos[e];
    size_t o = ((size_t)(b*L_+CTX_+t))*DM_ + d;
    *(float4*)&x[o] = v;
    union { u16 us[4]; uint2 q; } p;
    p.us[0]=f2b(v.x); p.us[1]=f2b(v.y); p.us[2]=f2b(v.z); p.us[3]=f2b(v.w);
    *(uint2*)&xb[o] = p.q;
}

// fp32 -> bf16, 8 elements/thread (n must be multiple of 2048)
__global__ __launch_bounds__(256) void k_f2b(const float* __restrict__ s, u16* __restrict__ d){
    int i = blockIdx.x*256 + threadIdx.x;
    int base = i*8;
    float4 a = *(const float4*)&s[base];
    float4 b = *(const float4*)&s[base+4];
    union { u16 us[8]; uint4 v; } o;
    o.us[0]=f2b(a.x); o.us[1]=f2b(a.y); o.us[2]=f2b(a.z); o.us[3]=f2b(a.w);
    o.us[4]=f2b(b.x); o.us[5]=f2b(b.y); o.us[6]=f2b(b.z); o.us[7]=f2b(b.w);
    *(uint4*)&d[base] = o.v;
}

// depthwise causal conv (kernel 4) + bias + silu; bf16 in, bf16 out
__global__ __launch_bounds__(256) void k_conv_silu(const u16* __restrict__ xzb, const float* __restrict__ cw,
                                                   const float* __restrict__ cb, u16* __restrict__ ub){
    int i = blockIdx.x*256 + threadIdx.x;        // MROWS_*DI_ = 2,621,440
    int d = i % DI_;
    int l = (i/DI_) % L_;
    int b = i/(DI_*L_);
    const u16* base = xzb + (size_t)b*L_*2048 + d;
    float acc = cb[d];
    #pragma unroll
    for (int k=0;k<DCONV_;++k){
        int ll = l-3+k;
        if (ll >= 0) acc = fmaf(b2f(base[(size_t)ll*2048]), cw[d*DCONV_+k], acc);
    }
    ub[i] = f2b(siluf_(acc));
}

// ---------------- bf16 MFMA GEMM, 128x128 tile, 4 waves (2x2), each wave 64x64 = 4x4 frags ----
// C[M,N] = A[M,K] * W[N,K]^T. If WB: write bf16 Cb only; else fp32 C (+bias).
#define LDST_ 40   // bf16 elems per LDS row (80 B)
template<bool WB>
__global__ __launch_bounds__(256) void k_mmx(const u16* __restrict__ A, int lda,
                                             const u16* __restrict__ Bw, int ldb,
                                             float* __restrict__ C, int ldc,
                                             const float* __restrict__ bias, int K,
                                             u16* __restrict__ Cb, int ldcb){
    __shared__ u16 As[128*LDST_];
    __shared__ u16 Bs[128*LDST_];
    int tid = threadIdx.x;
    int wave = tid >> 6, lane = tid & 63;
    int bm = blockIdx.y*128, bn = blockIdx.x*128;
    int wr = (wave>>1)*64, wc = (wave&1)*64;
    f32x4 acc[4][4] = {};
    int lrow = lane & 15, lk = (lane>>4)*8;
    for (int k0 = 0; k0 < K; k0 += 32){
        #pragma unroll
        for (int i=0;i<2;++i){
            int slot = tid + i*256;          // 0..511
            int rr = slot >> 2;              // 0..127
            int cc = (slot & 3) * 8;         // 0,8,16,24
            *(uint4*)&As[rr*LDST_+cc] = *(const uint4*)&A [(size_t)(bm+rr)*lda + k0 + cc];
            *(uint4*)&Bs[rr*LDST_+cc] = *(const uint4*)&Bw[(size_t)(bn+rr)*ldb + k0 + cc];
        }
        __syncthreads();
        bf16x8 af[4], bfr[4];
        #pragma unroll
        for (int f=0; f<4; ++f){
            af [f] = *(const bf16x8*)&As[(wr + f*16 + lrow)*LDST_ + lk];
            bfr[f] = *(const bf16x8*)&Bs[(wc + f*16 + lrow)*LDST_ + lk];
        }
        #pragma unroll
        for (int fm=0; fm<4; ++fm)
            #pragma unroll
            for (int fn=0; fn<4; ++fn)
                acc[fm][fn] = __builtin_amdgcn_mfma_f32_16x16x32_bf16(af[fm], bfr[fn], acc[fm][fn], 0,0,0);
        __syncthreads();
    }
    // C/D layout: col = lane&15, row = (lane>>4)*4 + j
    #pragma unroll
    for (int fm=0; fm<4; ++fm){
        int m0 = bm + wr + fm*16 + (lane>>4)*4;
        #pragma unroll
        for (int fn=0; fn<4; ++fn){
            int n = bn + wc + fn*16 + (lane&15);
            float bsv = (!WB && bias) ? bias[n] : 0.f;
            #pragma unroll
            for (int j=0; j<4; ++j){
                float v = acc[fm][fn][j] + bsv;
                if (WB) Cb[(size_t)(m0+j)*ldcb + n] = f2b(v);
                else    C [(size_t)(m0+j)*ldc  + n] = v;
            }
        }
    }
}

// ---------------- bf16 MFMA GEMM, 64x64 tile, 4 waves (2x2), each wave 32x32 = 2x2 frags ----
template<bool ACC, bool SPLIT>
__global__ __launch_bounds__(256) void k_mmx64(const u16* __restrict__ A, int lda,
                                               const u16* __restrict__ Bw, int ldb,
                                               float* __restrict__ C, int ldc,
                                               const float* __restrict__ bias, int ksteps,
                                               u16* __restrict__ Cb, int ldcb, int splitStride){
    __shared__ u16 As[64*LDST_];
    __shared__ u16 Bs[64*LDST_];
    int tid = threadIdx.x;
    int wave = tid >> 6, lane = tid & 63;
    int bm = blockIdx.y*64;
    int bn   = SPLIT ? 0 : blockIdx.x*64;
    int kbase= SPLIT ? blockIdx.x*ksteps*32 : 0;
    int wr = (wave>>1)*32, wc = (wave&1)*32;
    f32x4 acc[2][2] = {};
    int lrow = lane & 15, lk = (lane>>4)*8;
    int rr = tid >> 2, cc = (tid & 3) * 8;
    for (int s = 0; s < ksteps; ++s){
        int k0 = kbase + s*32;
        *(uint4*)&As[rr*LDST_+cc] = *(const uint4*)&A [(size_t)(bm+rr)*lda + k0 + cc];
        *(uint4*)&Bs[rr*LDST_+cc] = *(const uint4*)&Bw[(size_t)(bn+rr)*ldb + k0 + cc];
        __syncthreads();
        bf16x8 af[2], bfr[2];
        #pragma unroll
        for (int f=0; f<2; ++f){
            af [f] = *(const bf16x8*)&As[(wr + f*16 + lrow)*LDST_ + lk];
            bfr[f] = *(const bf16x8*)&Bs[(wc + f*16 + lrow)*LDST_ + lk];
        }
        #pragma unroll
        for (int fm=0; fm<2; ++fm)
            #pragma unroll
            for (int fn=0; fn<2; ++fn)
                acc[fm][fn] = __builtin_amdgcn_mfma_f32_16x16x32_bf16(af[fm], bfr[fn], acc[fm][fn], 0,0,0);
        __syncthreads();
    }
    float* Cout = SPLIT ? (C + (size_t)blockIdx.x*splitStride) : C;
    #pragma unroll
    for (int fm=0; fm<2; ++fm){
        int m0 = bm + wr + fm*16 + (lane>>4)*4;
        #pragma unroll
        for (int fn=0; fn<2; ++fn){
            int n = bn + wc + fn*16 + (lane&15);
            float bsv = (!SPLIT && bias) ? bias[n] : 0.f;
            #pragma unroll
            for (int j=0; j<4; ++j){
                float v = acc[fm][fn][j] + bsv;
                size_t off = (size_t)(m0+j)*ldc + n;
                if (ACC) v += Cout[off];
                Cout[off] = v;
                if (!SPLIT && Cb) Cb[(size_t)(m0+j)*ldcb + n] = f2b(v);
            }
        }
    }
}

// reduce 8 split partials
__global__ __launch_bounds__(256) void k_red8(const float* __restrict__ part, float* __restrict__ out){
    int j = (blockIdx.x*256 + threadIdx.x)*4;    // XDBL_N_/4 threads
    float4 s = *(const float4*)&part[j];
    #pragma unroll
    for (int p=1;p<8;++p){
        float4 t = *(const float4*)&part[(size_t)p*XDBL_N_ + j];
        s.x+=t.x; s.y+=t.y; s.z+=t.z; s.w+=t.w;
    }
    *(float4*)&out[j] = s;
}

// ---------------- fp32 tiled GEMM 64x64 (dpre: K=32) + softplus epilogue ----------------
template<bool SP>
__global__ __launch_bounds__(256) void k_mm(const float* __restrict__ A, int lda,
                                            const float* __restrict__ Bw, int ldb,
                                            float* __restrict__ C, int ldc,
                                            const float* __restrict__ bias, int K){
    __shared__ float As[32][68];
    __shared__ float Bs[32][68];
    int tid = threadIdx.x;
    int bm = blockIdx.y*64, bn = blockIdx.x*64;
    int tx = tid & 15, ty = tid >> 4;
    float acc[4][4] = {};
    for (int k0 = 0; k0 < K; k0 += 32){
        #pragma unroll
        for (int i=0;i<2;++i){
            int slot = tid + i*256;
            int r  = slot >> 3;
            int kv = (slot & 7) << 2;
            float4 a4 = *(const float4*)&A [(size_t)(bm+r)*lda + k0 + kv];
            As[kv+0][r]=a4.x; As[kv+1][r]=a4.y; As[kv+2][r]=a4.z; As[kv+3][r]=a4.w;
            float4 b4 = *(const float4*)&Bw[(size_t)(bn+r)*ldb + k0 + kv];
            Bs[kv+0][r]=b4.x; Bs[kv+1][r]=b4.y; Bs[kv+2][r]=b4.z; Bs[kv+3][r]=b4.w;
        }
        __syncthreads();
        #pragma unroll
        for (int k=0;k<32;++k){
            float4 av = *(const float4*)&As[k][ty*4];
            float4 bv = *(const float4*)&Bs[k][tx*4];
            float a_[4]={av.x,av.y,av.z,av.w};
            float b_[4]={bv.x,bv.y,bv.z,bv.w};
            #pragma unroll
            for (int ii=0;ii<4;++ii)
                #pragma unroll
                for (int jj=0;jj<4;++jj)
                    acc[ii][jj] = fmaf(a_[ii], b_[jj], acc[ii][jj]);
        }
        __syncthreads();
    }
    #pragma unroll
    for (int ii=0;ii<4;++ii){
        int m = bm + ty*4 + ii;
        #pragma unroll
        for (int jj=0;jj<4;++jj){
            int n = bn + tx*4 + jj;
            float v = acc[ii][jj];
            if (bias) v += bias[n];
            if (SP)   v  = softplusf_(v);
            C[(size_t)m*ldc + n] = v;
        }
    }
}

// ---------------- chunked selective scan, state-split 4-way ----------------
// block = (b, c, dgrp of 64 d); thread: dl = tid>>2 (d), sg = (tid&3)*4 (state base)
__global__ __launch_bounds__(256) void k_scan1(const float* __restrict__ dpre, const u16* __restrict__ ub,
                                               const float* __restrict__ xdbl, const float* __restrict__ Alog,
                                               float* __restrict__ hend, float* __restrict__ P){
    __shared__ float sDel[CL_*64];
    __shared__ u16   sU[CL_*64];
    __shared__ float sB[CL_*DS_];
    int blk = blockIdx.x;                         // B*NC*16 = 2560
    int dgrp = blk & 15;
    int c = (blk>>4) % NC_;
    int b = blk/(16*NC_);
    int d0 = dgrp*64;
    int tid = threadIdx.x;
    size_t rowbase = (size_t)(b*L_ + c*CL_);
    {
        int e = tid*4, st = e>>6, dd = e&63;
        size_t off = (rowbase+st)*DI_ + d0 + dd;
        *(float4*)&sDel[e] = *(const float4*)&dpre[off];
        *(uint2*)&sU[e]    = *(const uint2*)&ub[off];
        sB[tid] = xdbl[(rowbase + (tid>>4))*64 + 32 + (tid&15)];
    }
    __syncthreads();
    int dl = tid>>2, sg = (tid&3)*4;
    int d = d0 + dl;
    float A[4];
    #pragma unroll
    for (int i=0;i<4;++i) A[i] = -__expf(Alog[d*DS_ + sg + i]);
    float h[4] = {0,0,0,0}, Pl[4] = {1.f,1.f,1.f,1.f};
    #pragma unroll
    for (int t=0;t<CL_;++t){
        float delta = sDel[t*64+dl];
        float uu    = b2f(sU[t*64+dl]);
        float du    = delta*uu;
        #pragma unroll
        for (int i=0;i<4;++i){
            float a = __expf(delta*A[i]);
            h[i]  = fmaf(a, h[i], du*sB[t*DS_+sg+i]);
            Pl[i] *= a;
        }
    }
    size_t ob = ((size_t)((b*NC_+c)*DI_) + d)*DS_ + sg;
    *(float4*)&hend[ob] = make_float4(h[0],h[1],h[2],h[3]);
    *(float4*)&P[ob]    = make_float4(Pl[0],Pl[1],Pl[2],Pl[3]);
}

// pass 2: sequential combine across chunks; writes hstart IN-PLACE into hend
__global__ __launch_bounds__(256) void k_scan2(float* __restrict__ hend, const float* __restrict__ P){
    int g = blockIdx.x*256 + threadIdx.x;        // B*DI*DS = 32768
    int s = g % DS_;
    int d = (g/DS_) % DI_;
    int b = g/(DS_*DI_);
    float h = 0.f;
    for (int c=0;c<NC_;++c){
        size_t idx = ((size_t)((b*NC_+c)*DI_)+d)*DS_ + s;
        float he = hend[idx], p = P[idx];
        hend[idx] = h;
        h = fmaf(p, h, he);
    }
}

// pass 3: rerun chunk with correct initial state; gate; emit bf16 y
__global__ __launch_bounds__(256) void k_scan3(const float* __restrict__ dpre, const u16* __restrict__ ub,
                                               const float* __restrict__ xdbl, const u16* __restrict__ xzb,
                                               const float* __restrict__ Alog, const float* __restrict__ Dsk,
                                               const float* __restrict__ hstart, u16* __restrict__ yb){
    __shared__ float sDel[CL_*64];
    __shared__ u16   sU[CL_*64];
    __shared__ float sB[CL_*DS_], sC[CL_*DS_];
    __shared__ float sY[CL_*64];
    int blk = blockIdx.x;
    int dgrp = blk & 15;
    int c = (blk>>4) % NC_;
    int b = blk/(16*NC_);
    int d0 = dgrp*64;
    int tid = threadIdx.x;
    size_t rowbase = (size_t)(b*L_ + c*CL_);
    {
        int e = tid*4, st = e>>6, dd = e&63;
        size_t off = (rowbase+st)*DI_ + d0 + dd;
        *(float4*)&sDel[e] = *(const float4*)&dpre[off];
        *(uint2*)&sU[e]    = *(const uint2*)&ub[off];
        size_t rb = (rowbase + (tid>>4))*64;
        sB[tid] = xdbl[rb + 32 + (tid&15)];
        sC[tid] = xdbl[rb + 48 + (tid&15)];
    }
    __syncthreads();
    int dl = tid>>2, sg = (tid&3)*4;
    int d = d0 + dl;
    float A[4];
    #pragma unroll
    for (int i=0;i<4;++i) A[i] = -__expf(Alog[d*DS_ + sg + i]);
    size_t ib = ((size_t)((b*NC_+c)*DI_) + d)*DS_ + sg;
    float4 h4 = *(const float4*)&hstart[ib];
    float h[4] = {h4.x, h4.y, h4.z, h4.w};
    #pragma unroll
    for (int t=0;t<CL_;++t){
        float delta = sDel[t*64+dl];
        float uu    = b2f(sU[t*64+dl]);
        float du    = delta*uu;
        float yt = 0.f;
        #pragma unroll
        for (int i=0;i<4;++i){
            float a = __expf(delta*A[i]);
            h[i] = fmaf(a, h[i], du*sB[t*DS_+sg+i]);
            yt   = fmaf(h[i], sC[t*DS_+sg+i], yt);
        }
        yt += __shfl_xor(yt, 1);
        yt += __shfl_xor(yt, 2);
        if ((tid&3)==0) sY[t*64+dl] = yt;
    }
    __syncthreads();
    // gate phase: 4 elems/thread
    {
        int e = tid*4, st = e>>6, dd = e&63;
        size_t off = (rowbase+st)*DI_ + d0 + dd;
        float4 dskv = *(const float4*)&Dsk[d0+dd];
        uint2 zz = *(const uint2*)&xzb[(rowbase+st)*2048 + DI_ + d0 + dd];
        float z0 = __uint_as_float(zz.x<<16),  z1 = __uint_as_float(zz.x & 0xffff0000u);
        float z2 = __uint_as_float(zz.y<<16),  z3 = __uint_as_float(zz.y & 0xffff0000u);
        float u0 = b2f(sU[e+0]), u1 = b2f(sU[e+1]), u2 = b2f(sU[e+2]), u3 = b2f(sU[e+3]);
        union { u16 us[4]; uint2 q; } o;
        o.us[0] = f2b((sY[e+0] + u0*dskv.x) * siluf_(z0));
        o.us[1] = f2b((sY[e+1] + u1*dskv.y) * siluf_(z1));
        o.us[2] = f2b((sY[e+2] + u2*dskv.z) * siluf_(z2));
        o.us[3] = f2b((sY[e+3] + u3*dskv.w) * siluf_(z3));
        *(uint2*)&yb[off] = o.q;
    }
}

// ---------------- layernorm on target rows only, bf16 out ----------------
__global__ __launch_bounds__(256) void k_ln_tgt(const float* __restrict__ x, const float* __restrict__ g_,
                                                const float* __restrict__ b_, u16* __restrict__ xnb){
    int r = blockIdx.x;                           // 0..B*TGT-1
    int b = r / TGT_, t = r % TGT_;
    const float* row = x + ((size_t)(b*L_+CTX_+t))*DM_;
    int tid = threadIdx.x;
    float2 v = *(const float2*)&row[tid*2];
    float s = v.x+v.y, sq = v.x*v.x+v.y*v.y;
    #pragma unroll
    for (int off=32; off; off>>=1){ s += __shfl_down(s,off); sq += __shfl_down(sq,off); }
    __shared__ float ss[4], ssq[4];
    int w = tid>>6, ln = tid&63;
    if (ln==0){ ss[w]=s; ssq[w]=sq; }
    __syncthreads();
    if (tid==0){
        float S=ss[0]+ss[1]+ss[2]+ss[3], Q=ssq[0]+ssq[1]+ssq[2]+ssq[3];
        float mu = S/(float)DM_;
        float var = Q/(float)DM_ - mu*mu;
        ss[0]=mu; ssq[0]=rsqrtf(var+1e-5f);
    }
    __syncthreads();
    float mu=ss[0], rs=ssq[0];
    xnb[(size_t)r*DM_ + tid*2+0] = f2b((v.x-mu)*rs*g_[tid*2+0] + b_[tid*2+0]);
    xnb[(size_t)r*DM_ + tid*2+1] = f2b((v.y-mu)*rs*g_[tid*2+1] + b_[tid*2+1]);
}

// ---------------- host launch ----------------
extern "C" void kernel_launch(void* const* d_in, const int* in_sizes, int n_in,
                              void* d_out, int out_size, void* d_ws, size_t ws_size,
                              hipStream_t stream) {
    const float* ctx    = (const float*)d_in[0];
    const float* te     = (const float*)d_in[1];
    const float* ve     = (const float*)d_in[2];
    const float* pos_w  = (const float*)d_in[4];
    const float* pos_b  = (const float*)d_in[5];
    const float* outp_w = (const float*)d_in[6];
    const float* outp_b = (const float*)d_in[7];
    const float* ln_g   = (const float*)d_in[8];
    const float* ln_b   = (const float*)d_in[9];
    const float* in_w   = (const float*)d_in[10];
    const float* conv_w = (const float*)d_in[11];
    const float* conv_b = (const float*)d_in[12];
    const float* xproj_w= (const float*)d_in[13];
    const float* dt_w   = (const float*)d_in[14];
    const float* dt_b   = (const float*)d_in[15];
    const float* A_log  = (const float*)d_in[16];
    const float* D_skip = (const float*)d_in[17];
    const float* out_w  = (const float*)d_in[18];
    float* out = (float*)d_out;

    float* ws    = (float*)d_ws;
    float* x     = ws;                       // 1,310,720
    float* xdbl  = x     + 1310720;          //   163,840
    float* dpre  = xdbl  + 163840;           // 2,621,440
    float* pos   = dpre  + 2621440;          //   262,144
    float* hend  = pos   + 262144;           // 2,621,440
    float* P     = hend  + 2621440;          // 2,621,440
    float* xdblp = P     + 2621440;          // 1,310,720 (8 split partials)
    u16*  xb    = (u16*)(xdblp + 1310720);   // 1,310,720 u16
    u16*  tcb   = xb    + 1310720;           //   524,288
    u16*  yb    = tcb   + 524288;            // 2,621,440
    u16*  xnb   = yb    + 2621440;           //   262,144
    u16*  ub    = xnb   + 262144;            // 2,621,440
    u16*  xzb   = ub    + 2621440;           // 5,242,880
    u16*  inwb  = xzb   + 5242880;           // 2,097,152
    u16*  outwb = inwb  + 2097152;           // 1,048,576
    u16*  poswb = outwb + 1048576;           //   524,288
    u16*  outpwb= poswb + 524288;            //   262,144
    u16*  xpwb  = outpwb+ 262144;            //   131,072

    // weight conversions (bf16)
    k_f2b<<<1024, 256, 0, stream>>>(in_w,    inwb);
    k_f2b<<< 512, 256, 0, stream>>>(out_w,   outwb);
    k_f2b<<< 256, 256, 0, stream>>>(pos_w,   poswb);
    k_f2b<<< 128, 256, 0, stream>>>(outp_w,  outpwb);
    k_f2b<<<  64, 256, 0, stream>>>(xproj_w, xpwb);

    k_copy_ctx   <<<1024, 256, 0, stream>>>(ctx, x, xb);
    k_build_tc   <<< 512, 256, 0, stream>>>(te, ve, tcb);
    k_mmx64<false,false><<<dim3(8,8), 256, 0, stream>>>(tcb, 2*DM_, poswb, 2*DM_, pos, DM_, pos_b, 32, nullptr, 0, 0);
    k_scatter_pos<<< 256, 256, 0, stream>>>(pos, x, xb);

    for (int i=0;i<NL_;++i){
        const u16*   inwbi  = inwb + (size_t)i*2*DI_*DM_;
        const float* cw     = conv_w  + (size_t)i*DI_*DCONV_;
        const float* cb     = conv_b  + (size_t)i*DI_;
        const u16*   xpwbi  = xpwb + (size_t)i*(DTR_+2*DS_)*DI_;
        const float* dtw    = dt_w    + (size_t)i*DI_*DTR_;
        const float* dtb    = dt_b    + (size_t)i*DI_;
        const float* Ai     = A_log   + (size_t)i*DI_*DS_;
        const float* Dsk    = D_skip  + (size_t)i*DI_;
        const u16*   outwbi = outwb + (size_t)i*DM_*DI_;

        k_mmx<true><<<dim3(16,20), 256, 0, stream>>>(xb, DM_, inwbi, DM_, nullptr, 0, nullptr, DM_, xzb, 2*DI_);
        k_conv_silu <<<10240, 256, 0, stream>>>(xzb, cw, cb, ub);
        k_mmx64<false,true><<<dim3(8,40), 256, 0, stream>>>(ub, DI_, xpwbi, DI_, xdblp, 64, nullptr, 4, nullptr, 0, XDBL_N_);
        k_red8      <<<160, 256, 0, stream>>>(xdblp, xdbl);
        k_mm<true><<<dim3(16,40), 256, 0, stream>>>(xdbl, 64, dtw, DTR_, dpre, DI_, dtb, DTR_);
        k_scan1<<<2560, 256, 0, stream>>>(dpre, ub, xdbl, Ai, hend, P);
        k_scan2<<<128, 256, 0, stream>>>(hend, P);
        k_scan3<<<2560, 256, 0, stream>>>(dpre, ub, xdbl, xzb, Ai, Dsk, hend, yb);
        k_mmx64<true,false><<<dim3(8,40), 256, 0, stream>>>(yb, DI_, outwbi, DI_, x, DM_, nullptr, 32, xb, DM_, 0);
    }

    k_ln_tgt<<<512, 256, 0, stream>>>(x, ln_g, ln_b, xnb);
    k_mmx64<false,false><<<dim3(8,8), 256, 0, stream>>>(xnb, DM_, outpwb, DM_, out, DM_, outp_b, 16, nullptr, 0, 0);
}

// Round 6
// 250.593 us; speedup vs baseline: 3.1914x; 1.1076x over previous
//
#include <hip/hip_runtime.h>
#include <hip/hip_bf16.h>

// Problem constants (match reference)
#define B_     2
#define CTX_   1024
#define TGT_   256
#define DM_    512
#define L_     1280          // CTX + TGT
#define DI_    1024          // EXPAND * D_MODEL
#define DS_    16            // D_STATE
#define DCONV_ 4
#define NL_    2
#define DTR_   32            // DT_RANK
#define MROWS_ (B_*L_)       // 2560
#define NC_    80            // scan chunks
#define CL_    16            // chunk length (NC_*CL_ == L_)
#define XDBL_N_ (MROWS_*64)  // 163840

typedef unsigned short u16;
typedef __attribute__((ext_vector_type(8))) __bf16 bf16x8;
typedef __attribute__((ext_vector_type(4))) float f32x4;

__device__ __forceinline__ float sigmoidf_(float v){ return 1.f/(1.f+__expf(-v)); }
__device__ __forceinline__ float siluf_(float v){ return v*sigmoidf_(v); }
__device__ __forceinline__ float softplusf_(float v){ return (v>20.f)?v:log1pf(__expf(v)); }
__device__ __forceinline__ u16 f2b(float f){
    union { float f; unsigned u; } x; x.f = f;
    unsigned u = x.u;
    return (u16)((u + 0x7fffu + ((u>>16)&1u)) >> 16);
}
__device__ __forceinline__ float b2f(u16 v){ return __uint_as_float(((unsigned)v)<<16); }
__device__ __forceinline__ void gload_lds16(const void* g, void* l){
    __builtin_amdgcn_global_load_lds((const __attribute__((address_space(1))) unsigned*)g,
                                     (__attribute__((address_space(3))) unsigned*)l, 16, 0, 0);
}

// ---------------- fused weight fp32->bf16 (one launch) ----------------
#define G0_ 262144   // in_w    2,097,152
#define G1_ 131072   // out_w   1,048,576
#define G2_  65536   // pos_w     524,288
#define G3_  32768   // outp_w    262,144
#define G4_  16384   // xproj_w   131,072
__global__ __launch_bounds__(256) void k_f2b_all(const float* __restrict__ s0, const float* __restrict__ s1,
                                                 const float* __restrict__ s2, const float* __restrict__ s3,
                                                 const float* __restrict__ s4,
                                                 u16* d0, u16* d1, u16* d2, u16* d3, u16* d4){
    int g = blockIdx.x*256 + threadIdx.x;        // 507,904 total
    const float* s; u16* d; int base;
    if      (g < G0_)                { s=s0; d=d0; base=g*8; }
    else if (g < G0_+G1_)            { s=s1; d=d1; base=(g-G0_)*8; }
    else if (g < G0_+G1_+G2_)        { s=s2; d=d2; base=(g-G0_-G1_)*8; }
    else if (g < G0_+G1_+G2_+G3_)    { s=s3; d=d3; base=(g-G0_-G1_-G2_)*8; }
    else                             { s=s4; d=d4; base=(g-G0_-G1_-G2_-G3_)*8; }
    float4 a = *(const float4*)&s[base];
    float4 b = *(const float4*)&s[base+4];
    union { u16 us[8]; uint4 v; } o;
    o.us[0]=f2b(a.x); o.us[1]=f2b(a.y); o.us[2]=f2b(a.z); o.us[3]=f2b(a.w);
    o.us[4]=f2b(b.x); o.us[5]=f2b(b.y); o.us[6]=f2b(b.z); o.us[7]=f2b(b.w);
    *(uint4*)&d[base] = o.v;
}

// ---------------- fused prelude: ctx copy (blocks 0..1023) + tc build (1024..1535) ----------------
__global__ __launch_bounds__(256) void k_pre(const float* __restrict__ ctx, const float* __restrict__ te,
                                             const float* __restrict__ ve, float* __restrict__ x,
                                             u16* __restrict__ xb, u16* __restrict__ tcb){
    int blk = blockIdx.x;
    if (blk < 1024){
        int e = (blk*256 + threadIdx.x)*4;       // B*CTX*DM = 1,048,576
        int d = e % DM_;
        int l = (e/DM_) % CTX_;
        int b = e/(DM_*CTX_);
        float4 v = *(const float4*)&ctx[e];
        size_t o = ((size_t)(b*L_+l))*DM_ + d;
        *(float4*)&x[o] = v;
        union { u16 us[4]; uint2 q; } p;
        p.us[0]=f2b(v.x); p.us[1]=f2b(v.y); p.us[2]=f2b(v.z); p.us[3]=f2b(v.w);
        *(uint2*)&xb[o] = p.q;
    } else {
        int e = ((blk-1024)*256 + threadIdx.x)*4; // B*TGT*2DM = 524,288
        int k = e % (2*DM_);
        int r = e / (2*DM_);
        float4 v = (k < DM_) ? *(const float4*)&te[(size_t)r*DM_ + k]
                             : *(const float4*)&ve[(size_t)r*DM_ + (k-DM_)];
        union { u16 us[4]; uint2 q; } p;
        p.us[0]=f2b(v.x); p.us[1]=f2b(v.y); p.us[2]=f2b(v.z); p.us[3]=f2b(v.w);
        *(uint2*)&tcb[e] = p.q;
    }
}

// depthwise causal conv (kernel 4) + bias + silu; bf16 in/out, 4 d per thread
__global__ __launch_bounds__(256) void k_conv_silu(const u16* __restrict__ xzb, const float* __restrict__ cw,
                                                   const float* __restrict__ cb, u16* __restrict__ ub){
    int e = (blockIdx.x*256 + threadIdx.x)*4;    // MROWS_*DI_ = 2,621,440
    int d = e % DI_;
    int l = (e/DI_) % L_;
    int b = e/(DI_*L_);
    const u16* base = xzb + (size_t)b*L_*2048 + d;
    float4 w0 = *(const float4*)&cw[(d+0)*4];
    float4 w1 = *(const float4*)&cw[(d+1)*4];
    float4 w2 = *(const float4*)&cw[(d+2)*4];
    float4 w3 = *(const float4*)&cw[(d+3)*4];
    float4 bb = *(const float4*)&cb[d];
    float a0=bb.x, a1=bb.y, a2=bb.z, a3=bb.w;
    #pragma unroll
    for (int k=0;k<DCONV_;++k){
        int ll = l-3+k;
        if (ll >= 0){
            uint2 q = *(const uint2*)&base[(size_t)ll*2048];
            float x0=b2f((u16)(q.x&0xffffu)), x1=b2f((u16)(q.x>>16));
            float x2=b2f((u16)(q.y&0xffffu)), x3=b2f((u16)(q.y>>16));
            float c0 = (k==0)?w0.x:(k==1)?w0.y:(k==2)?w0.z:w0.w;
            float c1 = (k==0)?w1.x:(k==1)?w1.y:(k==2)?w1.z:w1.w;
            float c2 = (k==0)?w2.x:(k==1)?w2.y:(k==2)?w2.z:w2.w;
            float c3 = (k==0)?w3.x:(k==1)?w3.y:(k==2)?w3.z:w3.w;
            a0=fmaf(x0,c0,a0); a1=fmaf(x1,c1,a1); a2=fmaf(x2,c2,a2); a3=fmaf(x3,c3,a3);
        }
    }
    union { u16 us[4]; uint2 q; } o;
    o.us[0]=f2b(siluf_(a0)); o.us[1]=f2b(siluf_(a1));
    o.us[2]=f2b(siluf_(a2)); o.us[3]=f2b(siluf_(a3));
    *(uint2*)&ub[e] = o.q;
}

// ---------------- bf16 MFMA GEMM, 128x128 tile, global_load_lds + XOR-swizzled source ----
// LDS tile: 128 rows x 32 u16 (64B rows) = 8192 B per buffer -> TWO gload_lds16 issues
// per wave per buffer (4096 B each pass). Logical byte L=row*64+c stored at
// phys = L ^ (((L>>7)&7)<<4)  (involution; key bits 7-9 disjoint from mask bits 4-6).
template<bool WB>
__global__ __launch_bounds__(256) void k_mmx(const u16* __restrict__ A, int lda,
                                             const u16* __restrict__ Bw, int ldb,
                                             float* __restrict__ C, int ldc,
                                             const float* __restrict__ bias, int K,
                                             u16* __restrict__ Cb, int ldcb){
    __shared__ u16 As[128*32];
    __shared__ u16 Bs[128*32];
    int tid = threadIdx.x;
    int wave = tid >> 6, lane = tid & 63;
    int bm = blockIdx.y*128, bn = blockIdx.x*128;
    int wr = (wave>>1)*64, wc = (wave&1)*64;
    f32x4 acc[4][4] = {};
    int lrow = lane & 15, lk = (lane>>4)*8;
    // staging half 0: phys bytes [wave*1024 + lane*16]; half 1: +4096
    int dphys0 = wave*1024 + lane*16;
    int dphys1 = dphys0 + 4096;
    int alog0  = dphys0 ^ (((dphys0>>7)&7)<<4);
    int alog1  = dphys1 ^ (((dphys1>>7)&7)<<4);
    int grow0  = alog0 >> 6,        grow1  = alog1 >> 6;
    int gcol0  = (alog0 & 63) >> 1, gcol1  = (alog1 & 63) >> 1;
    u16* AsW0 = &As[wave*512];         u16* AsW1 = &As[2048 + wave*512];
    u16* BsW0 = &Bs[wave*512];         u16* BsW1 = &Bs[2048 + wave*512];
    int aoff[4], boff[4];
    #pragma unroll
    for (int f=0; f<4; ++f){
        int ra = wr + f*16 + lrow, rb = wc + f*16 + lrow;
        aoff[f] = (ra*64 + lk*2) ^ (((ra>>1)&7)<<4);
        boff[f] = (rb*64 + lk*2) ^ (((rb>>1)&7)<<4);
    }
    for (int k0 = 0; k0 < K; k0 += 32){
        gload_lds16(&A [(size_t)(bm+grow0)*lda + k0 + gcol0], AsW0);
        gload_lds16(&A [(size_t)(bm+grow1)*lda + k0 + gcol1], AsW1);
        gload_lds16(&Bw[(size_t)(bn+grow0)*ldb + k0 + gcol0], BsW0);
        gload_lds16(&Bw[(size_t)(bn+grow1)*ldb + k0 + gcol1], BsW1);
        __syncthreads();
        bf16x8 af[4], bfr[4];
        #pragma unroll
        for (int f=0; f<4; ++f){
            af [f] = *(const bf16x8*)((const char*)As + aoff[f]);
            bfr[f] = *(const bf16x8*)((const char*)Bs + boff[f]);
        }
        #pragma unroll
        for (int fm=0; fm<4; ++fm)
            #pragma unroll
            for (int fn=0; fn<4; ++fn)
                acc[fm][fn] = __builtin_amdgcn_mfma_f32_16x16x32_bf16(af[fm], bfr[fn], acc[fm][fn], 0,0,0);
        __syncthreads();
    }
    // C/D layout: col = lane&15, row = (lane>>4)*4 + j
    #pragma unroll
    for (int fm=0; fm<4; ++fm){
        int m0 = bm + wr + fm*16 + (lane>>4)*4;
        #pragma unroll
        for (int fn=0; fn<4; ++fn){
            int n = bn + wc + fn*16 + (lane&15);
            float bsv = (!WB && bias) ? bias[n] : 0.f;
            #pragma unroll
            for (int j=0; j<4; ++j){
                float v = acc[fm][fn][j] + bsv;
                if (WB) Cb[(size_t)(m0+j)*ldcb + n] = f2b(v);
                else    C [(size_t)(m0+j)*ldc  + n] = v;
            }
        }
    }
}

// ---------------- bf16 MFMA GEMM, 64x64 tile (4096 B tiles: single issue covers all) ----
// SPLIT: blockIdx.x = k-split; partial tile -> C + blockIdx.x*splitStride (bn=0).
// SCAT: remap output rows m(0..511) -> (m>>8)*L_ + CTX_ + (m&255); dual-write fp32 C + bf16 Cb.
template<bool ACC, bool SPLIT, bool SCAT>
__global__ __launch_bounds__(256) void k_mmx64(const u16* __restrict__ A, int lda,
                                               const u16* __restrict__ Bw, int ldb,
                                               float* __restrict__ C, int ldc,
                                               const float* __restrict__ bias, int ksteps,
                                               u16* __restrict__ Cb, int ldcb, int splitStride){
    __shared__ u16 As[64*32];
    __shared__ u16 Bs[64*32];
    int tid = threadIdx.x;
    int wave = tid >> 6, lane = tid & 63;
    int bm = blockIdx.y*64;
    int bn    = SPLIT ? 0 : blockIdx.x*64;
    int kbase = SPLIT ? blockIdx.x*ksteps*32 : 0;
    int wr = (wave>>1)*32, wc = (wave&1)*32;
    f32x4 acc[2][2] = {};
    int lrow = lane & 15, lk = (lane>>4)*8;
    int dphys = wave*1024 + lane*16;
    int alog  = dphys ^ (((dphys>>7)&7)<<4);
    int grow  = alog >> 6;
    int gcol  = (alog & 63) >> 1;
    u16* AsW = &As[wave*512];
    u16* BsW = &Bs[wave*512];
    int aoff[2], boff[2];
    #pragma unroll
    for (int f=0; f<2; ++f){
        int ra = wr + f*16 + lrow, rb = wc + f*16 + lrow;
        aoff[f] = (ra*64 + lk*2) ^ (((ra>>1)&7)<<4);
        boff[f] = (rb*64 + lk*2) ^ (((rb>>1)&7)<<4);
    }
    for (int s = 0; s < ksteps; ++s){
        int k0 = kbase + s*32;
        gload_lds16(&A [(size_t)(bm+grow)*lda + k0 + gcol], AsW);
        gload_lds16(&Bw[(size_t)(bn+grow)*ldb + k0 + gcol], BsW);
        __syncthreads();
        bf16x8 af[2], bfr[2];
        #pragma unroll
        for (int f=0; f<2; ++f){
            af [f] = *(const bf16x8*)((const char*)As + aoff[f]);
            bfr[f] = *(const bf16x8*)((const char*)Bs + boff[f]);
        }
        #pragma unroll
        for (int fm=0; fm<2; ++fm)
            #pragma unroll
            for (int fn=0; fn<2; ++fn)
                acc[fm][fn] = __builtin_amdgcn_mfma_f32_16x16x32_bf16(af[fm], bfr[fn], acc[fm][fn], 0,0,0);
        __syncthreads();
    }
    float* Cout = SPLIT ? (C + (size_t)blockIdx.x*splitStride) : C;
    #pragma unroll
    for (int fm=0; fm<2; ++fm){
        int m0 = bm + wr + fm*16 + (lane>>4)*4;
        #pragma unroll
        for (int fn=0; fn<2; ++fn){
            int n = bn + wc + fn*16 + (lane&15);
            float bsv = (!SPLIT && bias) ? bias[n] : 0.f;
            #pragma unroll
            for (int j=0; j<4; ++j){
                float v = acc[fm][fn][j] + bsv;
                int m = m0 + j;
                if (SCAT){
                    int xrow = (m>>8)*L_ + CTX_ + (m&255);
                    C [(size_t)xrow*ldc  + n] = v;
                    Cb[(size_t)xrow*ldcb + n] = f2b(v);
                } else {
                    size_t off = (size_t)m*ldc + n;
                    if (ACC) v += Cout[off];
                    Cout[off] = v;
                    if (!SPLIT && Cb) Cb[(size_t)m*ldcb + n] = f2b(v);
                }
            }
        }
    }
}

// reduce 8 split partials
__global__ __launch_bounds__(256) void k_red8(const float* __restrict__ part, float* __restrict__ out){
    int j = (blockIdx.x*256 + threadIdx.x)*4;    // XDBL_N_/4 threads
    float4 s = *(const float4*)&part[j];
    #pragma unroll
    for (int p=1;p<8;++p){
        float4 t = *(const float4*)&part[(size_t)p*XDBL_N_ + j];
        s.x+=t.x; s.y+=t.y; s.z+=t.z; s.w+=t.w;
    }
    *(float4*)&out[j] = s;
}

// ---------------- chunked selective scan, Δ-projection fused, state-split 4-way ----------------
// block = (b, c, dgrp of 64 d); thread: dl = tid>>2, sg = (tid&3)*4
__global__ __launch_bounds__(256) void k_scan1(const u16* __restrict__ ub, const float* __restrict__ xdbl,
                                               const float* __restrict__ dtw, const float* __restrict__ dtb,
                                               const float* __restrict__ Alog,
                                               float* __restrict__ hend, float* __restrict__ P){
    __shared__ float sX[CL_*64];      // xdbl rows [16][64] (dt 0:32 | B 32:48 | C 48:64)
    __shared__ float sW[64*33];       // dtw [64][32] padded
    __shared__ float sDtb[64];
    __shared__ float sDel[CL_*64];
    __shared__ u16   sU[CL_*64];
    int blk = blockIdx.x;             // B*NC*16 = 2560
    int dgrp = blk & 15;
    int c = (blk>>4) % NC_;
    int b = blk/(16*NC_);
    int d0 = dgrp*64;
    int tid = threadIdx.x;
    size_t rowbase = (size_t)(b*L_ + c*CL_);
    {
        int e = tid*4;
        *(float4*)&sX[e] = *(const float4*)&xdbl[rowbase*64 + e];
        int st=e>>6, dd=e&63;
        *(uint2*)&sU[e] = *(const uint2*)&ub[(rowbase+st)*DI_ + d0 + dd];
        int w0 = tid*8, dr = w0>>5, kk = w0&31;
        float4 wa = *(const float4*)&dtw[(size_t)(d0+dr)*DTR_ + kk];
        float4 wb = *(const float4*)&dtw[(size_t)(d0+dr)*DTR_ + kk + 4];
        sW[dr*33+kk+0]=wa.x; sW[dr*33+kk+1]=wa.y; sW[dr*33+kk+2]=wa.z; sW[dr*33+kk+3]=wa.w;
        sW[dr*33+kk+4]=wb.x; sW[dr*33+kk+5]=wb.y; sW[dr*33+kk+6]=wb.z; sW[dr*33+kk+7]=wb.w;
        if (tid < 64) sDtb[tid] = dtb[d0+tid];
    }
    __syncthreads();
    #pragma unroll
    for (int i=0;i<4;++i){
        int idx = tid + i*256;
        int t = idx>>6, dd = idx&63;
        float acc = sDtb[dd];
        #pragma unroll
        for (int k=0;k<DTR_;++k) acc = fmaf(sX[t*64+k], sW[dd*33+k], acc);
        sDel[idx] = softplusf_(acc);
    }
    __syncthreads();
    int dl = tid>>2, sg = (tid&3)*4;
    int d = d0 + dl;
    float A[4];
    #pragma unroll
    for (int i=0;i<4;++i) A[i] = -__expf(Alog[d*DS_ + sg + i]);
    float h[4] = {0,0,0,0}, Pl[4] = {1.f,1.f,1.f,1.f};
    #pragma unroll
    for (int t=0;t<CL_;++t){
        float delta = sDel[t*64+dl];
        float uu    = b2f(sU[t*64+dl]);
        float du    = delta*uu;
        #pragma unroll
        for (int i=0;i<4;++i){
            float a = __expf(delta*A[i]);
            h[i]  = fmaf(a, h[i], du*sX[t*64 + 32 + sg + i]);
            Pl[i] *= a;
        }
    }
    size_t ob = ((size_t)((b*NC_+c)*DI_) + d)*DS_ + sg;
    *(float4*)&hend[ob] = make_float4(h[0],h[1],h[2],h[3]);
    *(float4*)&P[ob]    = make_float4(Pl[0],Pl[1],Pl[2],Pl[3]);
}

// pass 2: sequential combine across chunks (8-deep load pipelining); hstart in-place into hend
__global__ __launch_bounds__(256) void k_scan2(float* __restrict__ hend, const float* __restrict__ P){
    int g = blockIdx.x*256 + threadIdx.x;        // B*DI*DS = 32768
    int s = g & 15;
    int d = (g>>4) & 1023;
    int b = g>>14;
    size_t base = ((size_t)b*NC_*DI_ + d)*DS_ + s;
    const size_t cs = (size_t)DI_*DS_;
    float h = 0.f;
    for (int c0=0;c0<NC_;c0+=8){
        float he[8], p[8];
        #pragma unroll
        for (int j=0;j<8;++j){ size_t idx = base + (size_t)(c0+j)*cs; he[j]=hend[idx]; p[j]=P[idx]; }
        #pragma unroll
        for (int j=0;j<8;++j){ size_t idx = base + (size_t)(c0+j)*cs; hend[idx]=h; h=fmaf(p[j],h,he[j]); }
    }
}

// pass 3: rerun chunk with correct initial state; Δ fused; gate; emit bf16 y
__global__ __launch_bounds__(256) void k_scan3(const u16* __restrict__ ub, const float* __restrict__ xdbl,
                                               const float* __restrict__ dtw, const float* __restrict__ dtb,
                                               const u16* __restrict__ xzb,
                                               const float* __restrict__ Alog, const float* __restrict__ Dsk,
                                               const float* __restrict__ hstart, u16* __restrict__ yb){
    __shared__ float sX[CL_*64];
    __shared__ float sW[64*33];
    __shared__ float sDtb[64];
    __shared__ float sDel[CL_*64];
    __shared__ u16   sU[CL_*64];
    __shared__ float sY[CL_*64];
    int blk = blockIdx.x;
    int dgrp = blk & 15;
    int c = (blk>>4) % NC_;
    int b = blk/(16*NC_);
    int d0 = dgrp*64;
    int tid = threadIdx.x;
    size_t rowbase = (size_t)(b*L_ + c*CL_);
    {
        int e = tid*4;
        *(float4*)&sX[e] = *(const float4*)&xdbl[rowbase*64 + e];
        int st=e>>6, dd=e&63;
        *(uint2*)&sU[e] = *(const uint2*)&ub[(rowbase+st)*DI_ + d0 + dd];
        int w0 = tid*8, dr = w0>>5, kk = w0&31;
        float4 wa = *(const float4*)&dtw[(size_t)(d0+dr)*DTR_ + kk];
        float4 wb = *(const float4*)&dtw[(size_t)(d0+dr)*DTR_ + kk + 4];
        sW[dr*33+kk+0]=wa.x; sW[dr*33+kk+1]=wa.y; sW[dr*33+kk+2]=wa.z; sW[dr*33+kk+3]=wa.w;
        sW[dr*33+kk+4]=wb.x; sW[dr*33+kk+5]=wb.y; sW[dr*33+kk+6]=wb.z; sW[dr*33+kk+7]=wb.w;
        if (tid < 64) sDtb[tid] = dtb[d0+tid];
    }
    __syncthreads();
    #pragma unroll
    for (int i=0;i<4;++i){
        int idx = tid + i*256;
        int t = idx>>6, dd = idx&63;
        float acc = sDtb[dd];
        #pragma unroll
        for (int k=0;k<DTR_;++k) acc = fmaf(sX[t*64+k], sW[dd*33+k], acc);
        sDel[idx] = softplusf_(acc);
    }
    __syncthreads();
    int dl = tid>>2, sg = (tid&3)*4;
    int d = d0 + dl;
    float A[4];
    #pragma unroll
    for (int i=0;i<4;++i) A[i] = -__expf(Alog[d*DS_ + sg + i]);
    size_t ib = ((size_t)((b*NC_+c)*DI_) + d)*DS_ + sg;
    float4 h4 = *(const float4*)&hstart[ib];
    float h[4] = {h4.x, h4.y, h4.z, h4.w};
    #pragma unroll
    for (int t=0;t<CL_;++t){
        float delta = sDel[t*64+dl];
        float uu    = b2f(sU[t*64+dl]);
        float du    = delta*uu;
        float yt = 0.f;
        #pragma unroll
        for (int i=0;i<4;++i){
            float a = __expf(delta*A[i]);
            h[i] = fmaf(a, h[i], du*sX[t*64 + 32 + sg + i]);
            yt   = fmaf(h[i], sX[t*64 + 48 + sg + i], yt);
        }
        yt += __shfl_xor(yt, 1);
        yt += __shfl_xor(yt, 2);
        if ((tid&3)==0) sY[t*64+dl] = yt;
    }
    __syncthreads();
    {
        int e = tid*4, st = e>>6, dd = e&63;
        size_t off = (rowbase+st)*DI_ + d0 + dd;
        float4 dskv = *(const float4*)&Dsk[d0+dd];
        uint2 zz = *(const uint2*)&xzb[(rowbase+st)*2048 + DI_ + d0 + dd];
        float z0 = __uint_as_float(zz.x<<16),  z1 = __uint_as_float(zz.x & 0xffff0000u);
        float z2 = __uint_as_float(zz.y<<16),  z3 = __uint_as_float(zz.y & 0xffff0000u);
        float u0 = b2f(sU[e+0]), u1 = b2f(sU[e+1]), u2 = b2f(sU[e+2]), u3 = b2f(sU[e+3]);
        union { u16 us[4]; uint2 q; } o;
        o.us[0] = f2b((sY[e+0] + u0*dskv.x) * siluf_(z0));
        o.us[1] = f2b((sY[e+1] + u1*dskv.y) * siluf_(z1));
        o.us[2] = f2b((sY[e+2] + u2*dskv.z) * siluf_(z2));
        o.us[3] = f2b((sY[e+3] + u3*dskv.w) * siluf_(z3));
        *(uint2*)&yb[off] = o.q;
    }
}

// ---------------- layernorm on target rows only, bf16 out ----------------
__global__ __launch_bounds__(256) void k_ln_tgt(const float* __restrict__ x, const float* __restrict__ g_,
                                                const float* __restrict__ b_, u16* __restrict__ xnb){
    int r = blockIdx.x;                           // 0..B*TGT-1
    int b = r / TGT_, t = r % TGT_;
    const float* row = x + ((size_t)(b*L_+CTX_+t))*DM_;
    int tid = threadIdx.x;
    float2 v = *(const float2*)&row[tid*2];
    float s = v.x+v.y, sq = v.x*v.x+v.y*v.y;
    #pragma unroll
    for (int off=32; off; off>>=1){ s += __shfl_down(s,off); sq += __shfl_down(sq,off); }
    __shared__ float ss[4], ssq[4];
    int w = tid>>6, ln = tid&63;
    if (ln==0){ ss[w]=s; ssq[w]=sq; }
    __syncthreads();
    if (tid==0){
        float S=ss[0]+ss[1]+ss[2]+ss[3], Q=ssq[0]+ssq[1]+ssq[2]+ssq[3];
        float mu = S/(float)DM_;
        float var = Q/(float)DM_ - mu*mu;
        ss[0]=mu; ssq[0]=rsqrtf(var+1e-5f);
    }
    __syncthreads();
    float mu=ss[0], rs=ssq[0];
    xnb[(size_t)r*DM_ + tid*2+0] = f2b((v.x-mu)*rs*g_[tid*2+0] + b_[tid*2+0]);
    xnb[(size_t)r*DM_ + tid*2+1] = f2b((v.y-mu)*rs*g_[tid*2+1] + b_[tid*2+1]);
}

// ---------------- host launch ----------------
extern "C" void kernel_launch(void* const* d_in, const int* in_sizes, int n_in,
                              void* d_out, int out_size, void* d_ws, size_t ws_size,
                              hipStream_t stream) {
    const float* ctx    = (const float*)d_in[0];
    const float* te     = (const float*)d_in[1];
    const float* ve     = (const float*)d_in[2];
    const float* pos_w  = (const float*)d_in[4];
    const float* pos_b  = (const float*)d_in[5];
    const float* outp_w = (const float*)d_in[6];
    const float* outp_b = (const float*)d_in[7];
    const float* ln_g   = (const float*)d_in[8];
    const float* ln_b   = (const float*)d_in[9];
    const float* in_w   = (const float*)d_in[10];
    const float* conv_w = (const float*)d_in[11];
    const float* conv_b = (const float*)d_in[12];
    const float* xproj_w= (const float*)d_in[13];
    const float* dt_w   = (const float*)d_in[14];
    const float* dt_b   = (const float*)d_in[15];
    const float* A_log  = (const float*)d_in[16];
    const float* D_skip = (const float*)d_in[17];
    const float* out_w  = (const float*)d_in[18];
    float* out = (float*)d_out;

    float* ws    = (float*)d_ws;
    float* x     = ws;                       // 1,310,720
    float* xdbl  = x     + 1310720;          //   163,840
    float* hend  = xdbl  + 163840;           // 2,621,440
    float* P     = hend  + 2621440;          // 2,621,440
    float* xdblp = P     + 2621440;          // 1,310,720 (8 split partials)
    u16*  xb    = (u16*)(xdblp + 1310720);   // 1,310,720 u16
    u16*  tcb   = xb    + 1310720;           //   524,288
    u16*  yb    = tcb   + 524288;            // 2,621,440
    u16*  xnb   = yb    + 2621440;           //   262,144
    u16*  ub    = xnb   + 262144;            // 2,621,440
    u16*  xzb   = ub    + 2621440;           // 5,242,880
    u16*  inwb  = xzb   + 5242880;           // 2,097,152
    u16*  outwb = inwb  + 2097152;           // 1,048,576
    u16*  poswb = outwb + 1048576;           //   524,288
    u16*  outpwb= poswb + 524288;            //   262,144
    u16*  xpwb  = outpwb+ 262144;            //   131,072

    k_f2b_all<<<1984, 256, 0, stream>>>(in_w, out_w, pos_w, outp_w, xproj_w,
                                        inwb, outwb, poswb, outpwb, xpwb);
    k_pre<<<1536, 256, 0, stream>>>(ctx, te, ve, x, xb, tcb);
    // pos projection, scattered directly into x/xb target rows
    k_mmx64<false,false,true><<<dim3(8,8), 256, 0, stream>>>(tcb, 2*DM_, poswb, 2*DM_, x, DM_, pos_b, 32, xb, DM_, 0);

    for (int i=0;i<NL_;++i){
        const u16*   inwbi  = inwb + (size_t)i*2*DI_*DM_;
        const float* cw     = conv_w  + (size_t)i*DI_*DCONV_;
        const float* cb     = conv_b  + (size_t)i*DI_;
        const u16*   xpwbi  = xpwb + (size_t)i*(DTR_+2*DS_)*DI_;
        const float* dtw    = dt_w    + (size_t)i*DI_*DTR_;
        const float* dtb    = dt_b    + (size_t)i*DI_;
        const float* Ai     = A_log   + (size_t)i*DI_*DS_;
        const float* Dsk    = D_skip  + (size_t)i*DI_;
        const u16*   outwbi = outwb + (size_t)i*DM_*DI_;

        k_mmx<true><<<dim3(16,20), 256, 0, stream>>>(xb, DM_, inwbi, DM_, nullptr, 0, nullptr, DM_, xzb, 2*DI_);
        k_conv_silu<<<2560, 256, 0, stream>>>(xzb, cw, cb, ub);
        k_mmx64<false,true,false><<<dim3(8,40), 256, 0, stream>>>(ub, DI_, xpwbi, DI_, xdblp, 64, nullptr, 4, nullptr, 0, XDBL_N_);
        k_red8<<<160, 256, 0, stream>>>(xdblp, xdbl);
        k_scan1<<<2560, 256, 0, stream>>>(ub, xdbl, dtw, dtb, Ai, hend, P);
        k_scan2<<<128, 256, 0, stream>>>(hend, P);
        k_scan3<<<2560, 256, 0, stream>>>(ub, xdbl, dtw, dtb, xzb, Ai, Dsk, hend, yb);
        k_mmx64<true,false,false><<<dim3(8,40), 256, 0, stream>>>(yb, DI_, outwbi, DI_, x, DM_, nullptr, 32, xb, DM_, 0);
    }

    k_ln_tgt<<<512, 256, 0, stream>>>(x, ln_g, ln_b, xnb);
    k_mmx64<false,false,false><<<dim3(8,8), 256, 0, stream>>>(xnb, DM_, outpwb, DM_, out, DM_, outp_b, 16, nullptr, 0, 0);
}

// Round 7
// 250.188 us; speedup vs baseline: 3.1965x; 1.0016x over previous
//
#include <hip/hip_runtime.h>
#include <hip/hip_bf16.h>

// Problem constants (match reference)
#define B_     2
#define CTX_   1024
#define TGT_   256
#define DM_    512
#define L_     1280          // CTX + TGT
#define DI_    1024          // EXPAND * D_MODEL
#define DS_    16            // D_STATE
#define DCONV_ 4
#define NL_    2
#define DTR_   32            // DT_RANK
#define MROWS_ (B_*L_)       // 2560
#define NC_    40            // scan chunks
#define CL_    32            // chunk length (NC_*CL_ == L_)
#define XDBL_N_ (MROWS_*64)  // 163840

typedef unsigned short u16;
typedef __attribute__((ext_vector_type(8))) __bf16 bf16x8;
typedef __attribute__((ext_vector_type(4))) float f32x4;

__device__ __forceinline__ float sigmoidf_(float v){ return 1.f/(1.f+__expf(-v)); }
__device__ __forceinline__ float siluf_(float v){ return v*sigmoidf_(v); }
__device__ __forceinline__ float softplusf_(float v){ return (v>20.f)?v:log1pf(__expf(v)); }
__device__ __forceinline__ u16 f2b(float f){
    union { float f; unsigned u; } x; x.f = f;
    unsigned u = x.u;
    return (u16)((u + 0x7fffu + ((u>>16)&1u)) >> 16);
}
__device__ __forceinline__ float b2f(u16 v){ return __uint_as_float(((unsigned)v)<<16); }
__device__ __forceinline__ void gload_lds16(const void* g, void* l){
    __builtin_amdgcn_global_load_lds((const __attribute__((address_space(1))) unsigned*)g,
                                     (__attribute__((address_space(3))) unsigned*)l, 16, 0, 0);
}
// 2-phase pipeline sync: wait own stage loads, pinned raw barrier
#define PIPE_SYNC do{ asm volatile("s_waitcnt vmcnt(0)" ::: "memory"); \
                      __builtin_amdgcn_sched_barrier(0); \
                      __builtin_amdgcn_s_barrier(); \
                      __builtin_amdgcn_sched_barrier(0); }while(0)

// ---------------- fused init: weight f2b (blocks 0..1983) + ctx/tc prelude (1984..3519) ----------------
#define G0_ 262144   // in_w    /8
#define G1_ 131072   // out_w
#define G2_  65536   // pos_w
#define G3_  32768   // outp_w
#define G4_  16384   // xproj_w
__global__ __launch_bounds__(256) void k_init(const float* __restrict__ s0, const float* __restrict__ s1,
                                              const float* __restrict__ s2, const float* __restrict__ s3,
                                              const float* __restrict__ s4,
                                              u16* d0, u16* d1, u16* d2, u16* d3, u16* d4,
                                              const float* __restrict__ ctx, const float* __restrict__ te,
                                              const float* __restrict__ ve, float* __restrict__ x,
                                              u16* __restrict__ xb, u16* __restrict__ tcb){
    int blk = blockIdx.x;
    if (blk < 1984){
        int g = blk*256 + threadIdx.x;
        const float* s; u16* d; int base;
        if      (g < G0_)                { s=s0; d=d0; base=g*8; }
        else if (g < G0_+G1_)            { s=s1; d=d1; base=(g-G0_)*8; }
        else if (g < G0_+G1_+G2_)        { s=s2; d=d2; base=(g-G0_-G1_)*8; }
        else if (g < G0_+G1_+G2_+G3_)    { s=s3; d=d3; base=(g-G0_-G1_-G2_)*8; }
        else                             { s=s4; d=d4; base=(g-G0_-G1_-G2_-G3_)*8; }
        float4 a = *(const float4*)&s[base];
        float4 b = *(const float4*)&s[base+4];
        union { u16 us[8]; uint4 v; } o;
        o.us[0]=f2b(a.x); o.us[1]=f2b(a.y); o.us[2]=f2b(a.z); o.us[3]=f2b(a.w);
        o.us[4]=f2b(b.x); o.us[5]=f2b(b.y); o.us[6]=f2b(b.z); o.us[7]=f2b(b.w);
        *(uint4*)&d[base] = o.v;
    } else if (blk < 1984+1024){
        int e = ((blk-1984)*256 + threadIdx.x)*4;   // B*CTX*DM
        int d = e % DM_;
        int l = (e/DM_) % CTX_;
        int b = e/(DM_*CTX_);
        float4 v = *(const float4*)&ctx[e];
        size_t o = ((size_t)(b*L_+l))*DM_ + d;
        *(float4*)&x[o] = v;
        union { u16 us[4]; uint2 q; } p;
        p.us[0]=f2b(v.x); p.us[1]=f2b(v.y); p.us[2]=f2b(v.z); p.us[3]=f2b(v.w);
        *(uint2*)&xb[o] = p.q;
    } else {
        int e = ((blk-1984-1024)*256 + threadIdx.x)*4; // B*TGT*2DM
        int k = e % (2*DM_);
        int r = e / (2*DM_);
        float4 v = (k < DM_) ? *(const float4*)&te[(size_t)r*DM_ + k]
                             : *(const float4*)&ve[(size_t)r*DM_ + (k-DM_)];
        union { u16 us[4]; uint2 q; } p;
        p.us[0]=f2b(v.x); p.us[1]=f2b(v.y); p.us[2]=f2b(v.z); p.us[3]=f2b(v.w);
        *(uint2*)&tcb[e] = p.q;
    }
}

// depthwise causal conv (kernel 4) + bias + silu; bf16 in/out, 4 d per thread
__global__ __launch_bounds__(256) void k_conv_silu(const u16* __restrict__ xzb, const float* __restrict__ cw,
                                                   const float* __restrict__ cb, u16* __restrict__ ub){
    int e = (blockIdx.x*256 + threadIdx.x)*4;    // MROWS_*DI_ = 2,621,440
    int d = e % DI_;
    int l = (e/DI_) % L_;
    int b = e/(DI_*L_);
    const u16* base = xzb + (size_t)b*L_*2048 + d;
    float4 w0 = *(const float4*)&cw[(d+0)*4];
    float4 w1 = *(const float4*)&cw[(d+1)*4];
    float4 w2 = *(const float4*)&cw[(d+2)*4];
    float4 w3 = *(const float4*)&cw[(d+3)*4];
    float4 bb = *(const float4*)&cb[d];
    float a0=bb.x, a1=bb.y, a2=bb.z, a3=bb.w;
    #pragma unroll
    for (int k=0;k<DCONV_;++k){
        int ll = l-3+k;
        if (ll >= 0){
            uint2 q = *(const uint2*)&base[(size_t)ll*2048];
            float x0=b2f((u16)(q.x&0xffffu)), x1=b2f((u16)(q.x>>16));
            float x2=b2f((u16)(q.y&0xffffu)), x3=b2f((u16)(q.y>>16));
            float c0 = (k==0)?w0.x:(k==1)?w0.y:(k==2)?w0.z:w0.w;
            float c1 = (k==0)?w1.x:(k==1)?w1.y:(k==2)?w1.z:w1.w;
            float c2 = (k==0)?w2.x:(k==1)?w2.y:(k==2)?w2.z:w2.w;
            float c3 = (k==0)?w3.x:(k==1)?w3.y:(k==2)?w3.z:w3.w;
            a0=fmaf(x0,c0,a0); a1=fmaf(x1,c1,a1); a2=fmaf(x2,c2,a2); a3=fmaf(x3,c3,a3);
        }
    }
    union { u16 us[4]; uint2 q; } o;
    o.us[0]=f2b(siluf_(a0)); o.us[1]=f2b(siluf_(a1));
    o.us[2]=f2b(siluf_(a2)); o.us[3]=f2b(siluf_(a3));
    *(uint2*)&ub[e] = o.q;
}

// ---------------- bf16 MFMA GEMM, 128x128 tile, 2-phase pipelined gload_lds + XOR-swizzle ----
template<bool WB>
__global__ __launch_bounds__(256) void k_mmx(const u16* __restrict__ A, int lda,
                                             const u16* __restrict__ Bw, int ldb,
                                             float* __restrict__ C, int ldc,
                                             const float* __restrict__ bias, int K,
                                             u16* __restrict__ Cb, int ldcb){
    __shared__ u16 As[2][128*32];
    __shared__ u16 Bs[2][128*32];
    int tid = threadIdx.x;
    int wave = tid >> 6, lane = tid & 63;
    int bm = blockIdx.y*128, bn = blockIdx.x*128;
    int wr = (wave>>1)*64, wc = (wave&1)*64;
    f32x4 acc[4][4] = {};
    int lrow = lane & 15, lk = (lane>>4)*8;
    int dphys0 = wave*1024 + lane*16;
    int dphys1 = dphys0 + 4096;
    int alog0  = dphys0 ^ (((dphys0>>7)&7)<<4);
    int alog1  = dphys1 ^ (((dphys1>>7)&7)<<4);
    int grow0  = alog0 >> 6,        grow1  = alog1 >> 6;
    int gcol0  = (alog0 & 63) >> 1, gcol1  = (alog1 & 63) >> 1;
    const u16* Ar0 = A  + (size_t)(bm+grow0)*lda + gcol0;
    const u16* Ar1 = A  + (size_t)(bm+grow1)*lda + gcol1;
    const u16* Br0 = Bw + (size_t)(bn+grow0)*ldb + gcol0;
    const u16* Br1 = Bw + (size_t)(bn+grow1)*ldb + gcol1;
    int aoff[4], boff[4];
    #pragma unroll
    for (int f=0; f<4; ++f){
        int ra = wr + f*16 + lrow, rb = wc + f*16 + lrow;
        aoff[f] = (ra*64 + lk*2) ^ (((ra>>1)&7)<<4);
        boff[f] = (rb*64 + lk*2) ^ (((rb>>1)&7)<<4);
    }
    int nt = K >> 5;
    auto stage = [&](int t, int buf){
        int k0 = t*32;
        gload_lds16(Ar0 + k0, &As[buf][wave*512]);
        gload_lds16(Ar1 + k0, &As[buf][2048 + wave*512]);
        gload_lds16(Br0 + k0, &Bs[buf][wave*512]);
        gload_lds16(Br1 + k0, &Bs[buf][2048 + wave*512]);
    };
    stage(0, 0);
    PIPE_SYNC;
    int cur = 0;
    for (int t=0; t<nt; ++t){
        if (t+1 < nt) stage(t+1, cur^1);
        bf16x8 af[4], bfr[4];
        #pragma unroll
        for (int f=0; f<4; ++f){
            af [f] = *(const bf16x8*)((const char*)As[cur] + aoff[f]);
            bfr[f] = *(const bf16x8*)((const char*)Bs[cur] + boff[f]);
        }
        #pragma unroll
        for (int fm=0; fm<4; ++fm)
            #pragma unroll
            for (int fn=0; fn<4; ++fn)
                acc[fm][fn] = __builtin_amdgcn_mfma_f32_16x16x32_bf16(af[fm], bfr[fn], acc[fm][fn], 0,0,0);
        PIPE_SYNC;
        cur ^= 1;
    }
    // C/D layout: col = lane&15, row = (lane>>4)*4 + j
    #pragma unroll
    for (int fm=0; fm<4; ++fm){
        int m0 = bm + wr + fm*16 + (lane>>4)*4;
        #pragma unroll
        for (int fn=0; fn<4; ++fn){
            int n = bn + wc + fn*16 + (lane&15);
            float bsv = (!WB && bias) ? bias[n] : 0.f;
            #pragma unroll
            for (int j=0; j<4; ++j){
                float v = acc[fm][fn][j] + bsv;
                if (WB) Cb[(size_t)(m0+j)*ldcb + n] = f2b(v);
                else    C [(size_t)(m0+j)*ldc  + n] = v;
            }
        }
    }
}

// ---------------- bf16 MFMA GEMM, 64x64 tile, 2-phase pipelined ----------------
// SPLIT: blockIdx.x = k-split; partial tile -> C + blockIdx.x*splitStride (bn=0).
// SCAT: remap output rows m(0..511) -> (m>>8)*L_ + CTX_ + (m&255); dual-write fp32 C + bf16 Cb.
template<bool ACC, bool SPLIT, bool SCAT>
__global__ __launch_bounds__(256) void k_mmx64(const u16* __restrict__ A, int lda,
                                               const u16* __restrict__ Bw, int ldb,
                                               float* __restrict__ C, int ldc,
                                               const float* __restrict__ bias, int ksteps,
                                               u16* __restrict__ Cb, int ldcb, int splitStride){
    __shared__ u16 As[2][64*32];
    __shared__ u16 Bs[2][64*32];
    int tid = threadIdx.x;
    int wave = tid >> 6, lane = tid & 63;
    int bm = blockIdx.y*64;
    int bn    = SPLIT ? 0 : blockIdx.x*64;
    int kbase = SPLIT ? blockIdx.x*ksteps*32 : 0;
    int wr = (wave>>1)*32, wc = (wave&1)*32;
    f32x4 acc[2][2] = {};
    int lrow = lane & 15, lk = (lane>>4)*8;
    int dphys = wave*1024 + lane*16;
    int alog  = dphys ^ (((dphys>>7)&7)<<4);
    int grow  = alog >> 6;
    int gcol  = (alog & 63) >> 1;
    const u16* Ar = A  + (size_t)(bm+grow)*lda + gcol;
    const u16* Br = Bw + (size_t)(bn+grow)*ldb + gcol;
    int aoff[2], boff[2];
    #pragma unroll
    for (int f=0; f<2; ++f){
        int ra = wr + f*16 + lrow, rb = wc + f*16 + lrow;
        aoff[f] = (ra*64 + lk*2) ^ (((ra>>1)&7)<<4);
        boff[f] = (rb*64 + lk*2) ^ (((rb>>1)&7)<<4);
    }
    auto stage = [&](int t, int buf){
        int k0 = kbase + t*32;
        gload_lds16(Ar + k0, &As[buf][wave*512]);
        gload_lds16(Br + k0, &Bs[buf][wave*512]);
    };
    stage(0, 0);
    PIPE_SYNC;
    int cur = 0;
    for (int t = 0; t < ksteps; ++t){
        if (t+1 < ksteps) stage(t+1, cur^1);
        bf16x8 af[2], bfr[2];
        #pragma unroll
        for (int f=0; f<2; ++f){
            af [f] = *(const bf16x8*)((const char*)As[cur] + aoff[f]);
            bfr[f] = *(const bf16x8*)((const char*)Bs[cur] + boff[f]);
        }
        #pragma unroll
        for (int fm=0; fm<2; ++fm)
            #pragma unroll
            for (int fn=0; fn<2; ++fn)
                acc[fm][fn] = __builtin_amdgcn_mfma_f32_16x16x32_bf16(af[fm], bfr[fn], acc[fm][fn], 0,0,0);
        PIPE_SYNC;
        cur ^= 1;
    }
    float* Cout = SPLIT ? (C + (size_t)blockIdx.x*splitStride) : C;
    #pragma unroll
    for (int fm=0; fm<2; ++fm){
        int m0 = bm + wr + fm*16 + (lane>>4)*4;
        #pragma unroll
        for (int fn=0; fn<2; ++fn){
            int n = bn + wc + fn*16 + (lane&15);
            float bsv = (!SPLIT && bias) ? bias[n] : 0.f;
            #pragma unroll
            for (int j=0; j<4; ++j){
                float v = acc[fm][fn][j] + bsv;
                int m = m0 + j;
                if (SCAT){
                    int xrow = (m>>8)*L_ + CTX_ + (m&255);
                    C [(size_t)xrow*ldc  + n] = v;
                    Cb[(size_t)xrow*ldcb + n] = f2b(v);
                } else {
                    size_t off = (size_t)m*ldc + n;
                    if (ACC) v += Cout[off];
                    Cout[off] = v;
                    if (!SPLIT && Cb) Cb[(size_t)m*ldcb + n] = f2b(v);
                }
            }
        }
    }
}

// reduce 8 split partials
__global__ __launch_bounds__(256) void k_red8(const float* __restrict__ part, float* __restrict__ out){
    int j = (blockIdx.x*256 + threadIdx.x)*4;    // XDBL_N_/4 threads
    float4 s = *(const float4*)&part[j];
    #pragma unroll
    for (int p=1;p<8;++p){
        float4 t = *(const float4*)&part[(size_t)p*XDBL_N_ + j];
        s.x+=t.x; s.y+=t.y; s.z+=t.z; s.w+=t.w;
    }
    *(float4*)&out[j] = s;
}

// ---------------- chunked selective scan (CL=32), Δ-projection fused, state-split 4-way ----------------
// block = (b, c, dgrp of 64 d); thread: dl = tid>>2, sg = (tid&3)*4
__global__ __launch_bounds__(256) void k_scan1(const u16* __restrict__ ub, const float* __restrict__ xdbl,
                                               const float* __restrict__ dtw, const float* __restrict__ dtb,
                                               const float* __restrict__ Alog,
                                               float* __restrict__ hend, float* __restrict__ P){
    __shared__ float sX[CL_*64];      // [32][64]: dt 0:32 | B 32:48 | C 48:64
    __shared__ float sW[64*33];       // dtw [64][32] padded
    __shared__ float sDtb[64];
    __shared__ float sDel[CL_*64];
    __shared__ u16   sU[CL_*64];
    int blk = blockIdx.x;             // B*NC*16 = 1280
    int dgrp = blk & 15;
    int c = (blk>>4) % NC_;
    int b = blk/(16*NC_);
    int d0 = dgrp*64;
    int tid = threadIdx.x;
    size_t rowbase = (size_t)(b*L_ + c*CL_);
    #pragma unroll
    for (int j=0;j<2;++j){
        int e = tid*4 + j*1024;
        *(float4*)&sX[e] = *(const float4*)&xdbl[rowbase*64 + e];
        int st=e>>6, dd=e&63;
        *(uint2*)&sU[e] = *(const uint2*)&ub[(rowbase+st)*DI_ + d0 + dd];
    }
    {
        int w0 = tid*8, dr = w0>>5, kk = w0&31;
        float4 wa = *(const float4*)&dtw[(size_t)(d0+dr)*DTR_ + kk];
        float4 wb = *(const float4*)&dtw[(size_t)(d0+dr)*DTR_ + kk + 4];
        sW[dr*33+kk+0]=wa.x; sW[dr*33+kk+1]=wa.y; sW[dr*33+kk+2]=wa.z; sW[dr*33+kk+3]=wa.w;
        sW[dr*33+kk+4]=wb.x; sW[dr*33+kk+5]=wb.y; sW[dr*33+kk+6]=wb.z; sW[dr*33+kk+7]=wb.w;
        if (tid < 64) sDtb[tid] = dtb[d0+tid];
    }
    __syncthreads();
    #pragma unroll
    for (int i=0;i<8;++i){
        int idx = tid + i*256;        // 0..2047
        int t = idx>>6, dd = idx&63;
        float acc = sDtb[dd];
        #pragma unroll
        for (int k=0;k<DTR_;++k) acc = fmaf(sX[t*64+k], sW[dd*33+k], acc);
        sDel[idx] = softplusf_(acc);
    }
    __syncthreads();
    int dl = tid>>2, sg = (tid&3)*4;
    int d = d0 + dl;
    float A[4];
    #pragma unroll
    for (int i=0;i<4;++i) A[i] = -__expf(Alog[d*DS_ + sg + i]);
    float h[4] = {0,0,0,0}, Pl[4] = {1.f,1.f,1.f,1.f};
    #pragma unroll
    for (int t=0;t<CL_;++t){
        float delta = sDel[t*64+dl];
        float uu    = b2f(sU[t*64+dl]);
        float du    = delta*uu;
        #pragma unroll
        for (int i=0;i<4;++i){
            float a = __expf(delta*A[i]);
            h[i]  = fmaf(a, h[i], du*sX[t*64 + 32 + sg + i]);
            Pl[i] *= a;
        }
    }
    size_t ob = ((size_t)((b*NC_+c)*DI_) + d)*DS_ + sg;
    *(float4*)&hend[ob] = make_float4(h[0],h[1],h[2],h[3]);
    *(float4*)&P[ob]    = make_float4(Pl[0],Pl[1],Pl[2],Pl[3]);
}

// pass 2: sequential combine across chunks (8-deep load pipelining); hstart in-place into hend
__global__ __launch_bounds__(256) void k_scan2(float* __restrict__ hend, const float* __restrict__ P){
    int g = blockIdx.x*256 + threadIdx.x;        // B*DI*DS = 32768
    int s = g & 15;
    int d = (g>>4) & 1023;
    int b = g>>14;
    size_t base = ((size_t)b*NC_*DI_ + d)*DS_ + s;
    const size_t cs = (size_t)DI_*DS_;
    float h = 0.f;
    for (int c0=0;c0<NC_;c0+=8){
        float he[8], p[8];
        #pragma unroll
        for (int j=0;j<8;++j){ size_t idx = base + (size_t)(c0+j)*cs; he[j]=hend[idx]; p[j]=P[idx]; }
        #pragma unroll
        for (int j=0;j<8;++j){ size_t idx = base + (size_t)(c0+j)*cs; hend[idx]=h; h=fmaf(p[j],h,he[j]); }
    }
}

// pass 3: rerun chunk with correct initial state; Δ fused; gate; emit bf16 y
__global__ __launch_bounds__(256) void k_scan3(const u16* __restrict__ ub, const float* __restrict__ xdbl,
                                               const float* __restrict__ dtw, const float* __restrict__ dtb,
                                               const u16* __restrict__ xzb,
                                               const float* __restrict__ Alog, const float* __restrict__ Dsk,
                                               const float* __restrict__ hstart, u16* __restrict__ yb){
    __shared__ float sX[CL_*64];
    __shared__ float sW[64*33];
    __shared__ float sDtb[64];
    __shared__ float sDel[CL_*64];
    __shared__ u16   sU[CL_*64];
    __shared__ float sY[CL_*64];
    int blk = blockIdx.x;
    int dgrp = blk & 15;
    int c = (blk>>4) % NC_;
    int b = blk/(16*NC_);
    int d0 = dgrp*64;
    int tid = threadIdx.x;
    size_t rowbase = (size_t)(b*L_ + c*CL_);
    #pragma unroll
    for (int j=0;j<2;++j){
        int e = tid*4 + j*1024;
        *(float4*)&sX[e] = *(const float4*)&xdbl[rowbase*64 + e];
        int st=e>>6, dd=e&63;
        *(uint2*)&sU[e] = *(const uint2*)&ub[(rowbase+st)*DI_ + d0 + dd];
    }
    {
        int w0 = tid*8, dr = w0>>5, kk = w0&31;
        float4 wa = *(const float4*)&dtw[(size_t)(d0+dr)*DTR_ + kk];
        float4 wb = *(const float4*)&dtw[(size_t)(d0+dr)*DTR_ + kk + 4];
        sW[dr*33+kk+0]=wa.x; sW[dr*33+kk+1]=wa.y; sW[dr*33+kk+2]=wa.z; sW[dr*33+kk+3]=wa.w;
        sW[dr*33+kk+4]=wb.x; sW[dr*33+kk+5]=wb.y; sW[dr*33+kk+6]=wb.z; sW[dr*33+kk+7]=wb.w;
        if (tid < 64) sDtb[tid] = dtb[d0+tid];
    }
    __syncthreads();
    #pragma unroll
    for (int i=0;i<8;++i){
        int idx = tid + i*256;
        int t = idx>>6, dd = idx&63;
        float acc = sDtb[dd];
        #pragma unroll
        for (int k=0;k<DTR_;++k) acc = fmaf(sX[t*64+k], sW[dd*33+k], acc);
        sDel[idx] = softplusf_(acc);
    }
    __syncthreads();
    int dl = tid>>2, sg = (tid&3)*4;
    int d = d0 + dl;
    float A[4];
    #pragma unroll
    for (int i=0;i<4;++i) A[i] = -__expf(Alog[d*DS_ + sg + i]);
    size_t ib = ((size_t)((b*NC_+c)*DI_) + d)*DS_ + sg;
    float4 h4 = *(const float4*)&hstart[ib];
    float h[4] = {h4.x, h4.y, h4.z, h4.w};
    #pragma unroll
    for (int t=0;t<CL_;++t){
        float delta = sDel[t*64+dl];
        float uu    = b2f(sU[t*64+dl]);
        float du    = delta*uu;
        float yt = 0.f;
        #pragma unroll
        for (int i=0;i<4;++i){
            float a = __expf(delta*A[i]);
            h[i] = fmaf(a, h[i], du*sX[t*64 + 32 + sg + i]);
            yt   = fmaf(h[i], sX[t*64 + 48 + sg + i], yt);
        }
        yt += __shfl_xor(yt, 1);
        yt += __shfl_xor(yt, 2);
        if ((tid&3)==0) sY[t*64+dl] = yt;
    }
    __syncthreads();
    #pragma unroll
    for (int j=0;j<2;++j){
        int e = tid*4 + j*1024, st = e>>6, dd = e&63;
        size_t off = (rowbase+st)*DI_ + d0 + dd;
        float4 dskv = *(const float4*)&Dsk[d0+dd];
        uint2 zz = *(const uint2*)&xzb[(rowbase+st)*2048 + DI_ + d0 + dd];
        float z0 = __uint_as_float(zz.x<<16),  z1 = __uint_as_float(zz.x & 0xffff0000u);
        float z2 = __uint_as_float(zz.y<<16),  z3 = __uint_as_float(zz.y & 0xffff0000u);
        float u0 = b2f(sU[e+0]), u1 = b2f(sU[e+1]), u2 = b2f(sU[e+2]), u3 = b2f(sU[e+3]);
        union { u16 us[4]; uint2 q; } o;
        o.us[0] = f2b((sY[e+0] + u0*dskv.x) * siluf_(z0));
        o.us[1] = f2b((sY[e+1] + u1*dskv.y) * siluf_(z1));
        o.us[2] = f2b((sY[e+2] + u2*dskv.z) * siluf_(z2));
        o.us[3] = f2b((sY[e+3] + u3*dskv.w) * siluf_(z3));
        *(uint2*)&yb[off] = o.q;
    }
}

// ---------------- layernorm on target rows only, bf16 out ----------------
__global__ __launch_bounds__(256) void k_ln_tgt(const float* __restrict__ x, const float* __restrict__ g_,
                                                const float* __restrict__ b_, u16* __restrict__ xnb){
    int r = blockIdx.x;                           // 0..B*TGT-1
    int b = r / TGT_, t = r % TGT_;
    const float* row = x + ((size_t)(b*L_+CTX_+t))*DM_;
    int tid = threadIdx.x;
    float2 v = *(const float2*)&row[tid*2];
    float s = v.x+v.y, sq = v.x*v.x+v.y*v.y;
    #pragma unroll
    for (int off=32; off; off>>=1){ s += __shfl_down(s,off); sq += __shfl_down(sq,off); }
    __shared__ float ss[4], ssq[4];
    int w = tid>>6, ln = tid&63;
    if (ln==0){ ss[w]=s; ssq[w]=sq; }
    __syncthreads();
    if (tid==0){
        float S=ss[0]+ss[1]+ss[2]+ss[3], Q=ssq[0]+ssq[1]+ssq[2]+ssq[3];
        float mu = S/(float)DM_;
        float var = Q/(float)DM_ - mu*mu;
        ss[0]=mu; ssq[0]=rsqrtf(var+1e-5f);
    }
    __syncthreads();
    float mu=ss[0], rs=ssq[0];
    xnb[(size_t)r*DM_ + tid*2+0] = f2b((v.x-mu)*rs*g_[tid*2+0] + b_[tid*2+0]);
    xnb[(size_t)r*DM_ + tid*2+1] = f2b((v.y-mu)*rs*g_[tid*2+1] + b_[tid*2+1]);
}

// ---------------- host launch ----------------
extern "C" void kernel_launch(void* const* d_in, const int* in_sizes, int n_in,
                              void* d_out, int out_size, void* d_ws, size_t ws_size,
                              hipStream_t stream) {
    const float* ctx    = (const float*)d_in[0];
    const float* te     = (const float*)d_in[1];
    const float* ve     = (const float*)d_in[2];
    const float* pos_w  = (const float*)d_in[4];
    const float* pos_b  = (const float*)d_in[5];
    const float* outp_w = (const float*)d_in[6];
    const float* outp_b = (const float*)d_in[7];
    const float* ln_g   = (const float*)d_in[8];
    const float* ln_b   = (const float*)d_in[9];
    const float* in_w   = (const float*)d_in[10];
    const float* conv_w = (const float*)d_in[11];
    const float* conv_b = (const float*)d_in[12];
    const float* xproj_w= (const float*)d_in[13];
    const float* dt_w   = (const float*)d_in[14];
    const float* dt_b   = (const float*)d_in[15];
    const float* A_log  = (const float*)d_in[16];
    const float* D_skip = (const float*)d_in[17];
    const float* out_w  = (const float*)d_in[18];
    float* out = (float*)d_out;

    float* ws    = (float*)d_ws;
    float* x     = ws;                       // 1,310,720
    float* xdbl  = x     + 1310720;          //   163,840
    float* hend  = xdbl  + 163840;           // 1,310,720 (B*NC*DI*DS)
    float* P     = hend  + 1310720;          // 1,310,720
    float* xdblp = P     + 1310720;          // 1,310,720 (8 split partials)
    u16*  xb    = (u16*)(xdblp + 1310720);   // 1,310,720 u16
    u16*  tcb   = xb    + 1310720;           //   524,288
    u16*  yb    = tcb   + 524288;            // 2,621,440
    u16*  xnb   = yb    + 2621440;           //   262,144
    u16*  ub    = xnb   + 262144;            // 2,621,440
    u16*  xzb   = ub    + 2621440;           // 5,242,880
    u16*  inwb  = xzb   + 5242880;           // 2,097,152
    u16*  outwb = inwb  + 2097152;           // 1,048,576
    u16*  poswb = outwb + 1048576;           //   524,288
    u16*  outpwb= poswb + 524288;            //   262,144
    u16*  xpwb  = outpwb+ 262144;            //   131,072

    k_init<<<3520, 256, 0, stream>>>(in_w, out_w, pos_w, outp_w, xproj_w,
                                     inwb, outwb, poswb, outpwb, xpwb,
                                     ctx, te, ve, x, xb, tcb);
    // pos projection, scattered directly into x/xb target rows
    k_mmx64<false,false,true><<<dim3(8,8), 256, 0, stream>>>(tcb, 2*DM_, poswb, 2*DM_, x, DM_, pos_b, 32, xb, DM_, 0);

    for (int i=0;i<NL_;++i){
        const u16*   inwbi  = inwb + (size_t)i*2*DI_*DM_;
        const float* cw     = conv_w  + (size_t)i*DI_*DCONV_;
        const float* cb     = conv_b  + (size_t)i*DI_;
        const u16*   xpwbi  = xpwb + (size_t)i*(DTR_+2*DS_)*DI_;
        const float* dtw    = dt_w    + (size_t)i*DI_*DTR_;
        const float* dtb    = dt_b    + (size_t)i*DI_;
        const float* Ai     = A_log   + (size_t)i*DI_*DS_;
        const float* Dsk    = D_skip  + (size_t)i*DI_;
        const u16*   outwbi = outwb + (size_t)i*DM_*DI_;

        k_mmx<true><<<dim3(16,20), 256, 0, stream>>>(xb, DM_, inwbi, DM_, nullptr, 0, nullptr, DM_, xzb, 2*DI_);
        k_conv_silu<<<2560, 256, 0, stream>>>(xzb, cw, cb, ub);
        k_mmx64<false,true,false><<<dim3(8,40), 256, 0, stream>>>(ub, DI_, xpwbi, DI_, xdblp, 64, nullptr, 4, nullptr, 0, XDBL_N_);
        k_red8<<<160, 256, 0, stream>>>(xdblp, xdbl);
        k_scan1<<<1280, 256, 0, stream>>>(ub, xdbl, dtw, dtb, Ai, hend, P);
        k_scan2<<<128, 256, 0, stream>>>(hend, P);
        k_scan3<<<1280, 256, 0, stream>>>(ub, xdbl, dtw, dtb, xzb, Ai, Dsk, hend, yb);
        k_mmx64<true,false,false><<<dim3(8,40), 256, 0, stream>>>(yb, DI_, outwbi, DI_, x, DM_, nullptr, 32, xb, DM_, 0);
    }

    k_ln_tgt<<<512, 256, 0, stream>>>(x, ln_g, ln_b, xnb);
    k_mmx64<false,false,false><<<dim3(8,8), 256, 0, stream>>>(xnb, DM_, outpwb, DM_, out, DM_, outp_b, 16, nullptr, 0, 0);
}

// Round 8
// 238.158 us; speedup vs baseline: 3.3580x; 1.0505x over previous
//
#include <hip/hip_runtime.h>
#include <hip/hip_bf16.h>

// Problem constants (match reference)
#define B_     2
#define CTX_   1024
#define TGT_   256
#define DM_    512
#define L_     1280          // CTX + TGT
#define DI_    1024          // EXPAND * D_MODEL
#define DS_    16            // D_STATE
#define DCONV_ 4
#define NL_    2
#define DTR_   32            // DT_RANK
#define MROWS_ (B_*L_)       // 2560
#define NC_    80            // scan chunks
#define CL_    16            // chunk length (NC_*CL_ == L_)
#define XDBL_N_ (MROWS_*64)  // 163840

typedef unsigned short u16;
typedef __attribute__((ext_vector_type(8))) __bf16 bf16x8;
typedef __attribute__((ext_vector_type(4))) float f32x4;

__device__ __forceinline__ float sigmoidf_(float v){ return 1.f/(1.f+__expf(-v)); }
__device__ __forceinline__ float siluf_(float v){ return v*sigmoidf_(v); }
__device__ __forceinline__ float softplusf_(float v){ return (v>20.f)?v:log1pf(__expf(v)); }
__device__ __forceinline__ u16 f2b(float f){
    union { float f; unsigned u; } x; x.f = f;
    unsigned u = x.u;
    return (u16)((u + 0x7fffu + ((u>>16)&1u)) >> 16);
}
__device__ __forceinline__ float b2f(u16 v){ return __uint_as_float(((unsigned)v)<<16); }
__device__ __forceinline__ void gload_lds16(const void* g, void* l){
    __builtin_amdgcn_global_load_lds((const __attribute__((address_space(1))) unsigned*)g,
                                     (__attribute__((address_space(3))) unsigned*)l, 16, 0, 0);
}
// 2-phase pipeline sync: wait own stage loads, pinned raw barrier
#define PIPE_SYNC do{ asm volatile("s_waitcnt vmcnt(0)" ::: "memory"); \
                      __builtin_amdgcn_sched_barrier(0); \
                      __builtin_amdgcn_s_barrier(); \
                      __builtin_amdgcn_sched_barrier(0); }while(0)

// ---------------- fused init: weight f2b (blocks 0..1983) + ctx/tc prelude (1984..3519) ----------------
#define G0_ 262144   // in_w    /8
#define G1_ 131072   // out_w
#define G2_  65536   // pos_w
#define G3_  32768   // outp_w
#define G4_  16384   // xproj_w
__global__ __launch_bounds__(256) void k_init(const float* __restrict__ s0, const float* __restrict__ s1,
                                              const float* __restrict__ s2, const float* __restrict__ s3,
                                              const float* __restrict__ s4,
                                              u16* d0, u16* d1, u16* d2, u16* d3, u16* d4,
                                              const float* __restrict__ ctx, const float* __restrict__ te,
                                              const float* __restrict__ ve, float* __restrict__ x,
                                              u16* __restrict__ xb, u16* __restrict__ tcb){
    int blk = blockIdx.x;
    if (blk < 1984){
        int g = blk*256 + threadIdx.x;
        const float* s; u16* d; int base;
        if      (g < G0_)                { s=s0; d=d0; base=g*8; }
        else if (g < G0_+G1_)            { s=s1; d=d1; base=(g-G0_)*8; }
        else if (g < G0_+G1_+G2_)        { s=s2; d=d2; base=(g-G0_-G1_)*8; }
        else if (g < G0_+G1_+G2_+G3_)    { s=s3; d=d3; base=(g-G0_-G1_-G2_)*8; }
        else                             { s=s4; d=d4; base=(g-G0_-G1_-G2_-G3_)*8; }
        float4 a = *(const float4*)&s[base];
        float4 b = *(const float4*)&s[base+4];
        union { u16 us[8]; uint4 v; } o;
        o.us[0]=f2b(a.x); o.us[1]=f2b(a.y); o.us[2]=f2b(a.z); o.us[3]=f2b(a.w);
        o.us[4]=f2b(b.x); o.us[5]=f2b(b.y); o.us[6]=f2b(b.z); o.us[7]=f2b(b.w);
        *(uint4*)&d[base] = o.v;
    } else if (blk < 1984+1024){
        int e = ((blk-1984)*256 + threadIdx.x)*4;   // B*CTX*DM
        int d = e % DM_;
        int l = (e/DM_) % CTX_;
        int b = e/(DM_*CTX_);
        float4 v = *(const float4*)&ctx[e];
        size_t o = ((size_t)(b*L_+l))*DM_ + d;
        *(float4*)&x[o] = v;
        union { u16 us[4]; uint2 q; } p;
        p.us[0]=f2b(v.x); p.us[1]=f2b(v.y); p.us[2]=f2b(v.z); p.us[3]=f2b(v.w);
        *(uint2*)&xb[o] = p.q;
    } else {
        int e = ((blk-1984-1024)*256 + threadIdx.x)*4; // B*TGT*2DM
        int k = e % (2*DM_);
        int r = e / (2*DM_);
        float4 v = (k < DM_) ? *(const float4*)&te[(size_t)r*DM_ + k]
                             : *(const float4*)&ve[(size_t)r*DM_ + (k-DM_)];
        union { u16 us[4]; uint2 q; } p;
        p.us[0]=f2b(v.x); p.us[1]=f2b(v.y); p.us[2]=f2b(v.z); p.us[3]=f2b(v.w);
        *(uint2*)&tcb[e] = p.q;
    }
}

// depthwise causal conv (kernel 4) + bias + silu; bf16 in/out, 4 d per thread
__global__ __launch_bounds__(256) void k_conv_silu(const u16* __restrict__ xzb, const float* __restrict__ cw,
                                                   const float* __restrict__ cb, u16* __restrict__ ub){
    int e = (blockIdx.x*256 + threadIdx.x)*4;    // MROWS_*DI_ = 2,621,440
    int d = e % DI_;
    int l = (e/DI_) % L_;
    int b = e/(DI_*L_);
    const u16* base = xzb + (size_t)b*L_*2048 + d;
    float4 w0 = *(const float4*)&cw[(d+0)*4];
    float4 w1 = *(const float4*)&cw[(d+1)*4];
    float4 w2 = *(const float4*)&cw[(d+2)*4];
    float4 w3 = *(const float4*)&cw[(d+3)*4];
    float4 bb = *(const float4*)&cb[d];
    float a0=bb.x, a1=bb.y, a2=bb.z, a3=bb.w;
    #pragma unroll
    for (int k=0;k<DCONV_;++k){
        int ll = l-3+k;
        if (ll >= 0){
            uint2 q = *(const uint2*)&base[(size_t)ll*2048];
            float x0=b2f((u16)(q.x&0xffffu)), x1=b2f((u16)(q.x>>16));
            float x2=b2f((u16)(q.y&0xffffu)), x3=b2f((u16)(q.y>>16));
            float c0 = (k==0)?w0.x:(k==1)?w0.y:(k==2)?w0.z:w0.w;
            float c1 = (k==0)?w1.x:(k==1)?w1.y:(k==2)?w1.z:w1.w;
            float c2 = (k==0)?w2.x:(k==1)?w2.y:(k==2)?w2.z:w2.w;
            float c3 = (k==0)?w3.x:(k==1)?w3.y:(k==2)?w3.z:w3.w;
            a0=fmaf(x0,c0,a0); a1=fmaf(x1,c1,a1); a2=fmaf(x2,c2,a2); a3=fmaf(x3,c3,a3);
        }
    }
    union { u16 us[4]; uint2 q; } o;
    o.us[0]=f2b(siluf_(a0)); o.us[1]=f2b(siluf_(a1));
    o.us[2]=f2b(siluf_(a2)); o.us[3]=f2b(siluf_(a3));
    *(uint2*)&ub[e] = o.q;
}

// ---------------- bf16 MFMA GEMM, 128x128 tile, 8 waves (2x4 of 64x32), 2-phase pipelined ----
// LDS 8KB/matrix/buf; 512 threads x 16B = 8KB per issue -> one issue per matrix per stage.
template<bool WB>
__global__ __launch_bounds__(512) void k_mmx(const u16* __restrict__ A, int lda,
                                             const u16* __restrict__ Bw, int ldb,
                                             float* __restrict__ C, int ldc,
                                             const float* __restrict__ bias, int K,
                                             u16* __restrict__ Cb, int ldcb){
    __shared__ u16 As[2][128*32];
    __shared__ u16 Bs[2][128*32];
    int tid = threadIdx.x;
    int wave = tid >> 6, lane = tid & 63;
    int bm = blockIdx.y*128, bn = blockIdx.x*128;
    int wr = (wave>>2)*64, wc = (wave&3)*32;
    f32x4 acc[4][2] = {};
    int lrow = lane & 15, lk = (lane>>4)*8;
    int dphys = tid*16;                    // 0..8191
    int alog  = dphys ^ (((dphys>>7)&7)<<4);
    int grow  = alog >> 6;                 // 0..127
    int gcol  = (alog & 63) >> 1;
    const u16* Ar = A  + (size_t)(bm+grow)*lda + gcol;
    const u16* Br = Bw + (size_t)(bn+grow)*ldb + gcol;
    int aoff[4], boff[2];
    #pragma unroll
    for (int f=0; f<4; ++f){
        int ra = wr + f*16 + lrow;
        aoff[f] = (ra*64 + lk*2) ^ (((ra>>1)&7)<<4);
    }
    #pragma unroll
    for (int f=0; f<2; ++f){
        int rb = wc + f*16 + lrow;
        boff[f] = (rb*64 + lk*2) ^ (((rb>>1)&7)<<4);
    }
    int nt = K >> 5;
    auto stage = [&](int t, int buf){
        int k0 = t*32;
        gload_lds16(Ar + k0, &As[buf][wave*512]);
        gload_lds16(Br + k0, &Bs[buf][wave*512]);
    };
    stage(0, 0);
    PIPE_SYNC;
    int cur = 0;
    for (int t=0; t<nt; ++t){
        if (t+1 < nt) stage(t+1, cur^1);
        bf16x8 af[4], bfr[2];
        #pragma unroll
        for (int f=0; f<4; ++f) af[f]  = *(const bf16x8*)((const char*)As[cur] + aoff[f]);
        #pragma unroll
        for (int f=0; f<2; ++f) bfr[f] = *(const bf16x8*)((const char*)Bs[cur] + boff[f]);
        #pragma unroll
        for (int fm=0; fm<4; ++fm)
            #pragma unroll
            for (int fn=0; fn<2; ++fn)
                acc[fm][fn] = __builtin_amdgcn_mfma_f32_16x16x32_bf16(af[fm], bfr[fn], acc[fm][fn], 0,0,0);
        PIPE_SYNC;
        cur ^= 1;
    }
    // C/D layout: col = lane&15, row = (lane>>4)*4 + j
    #pragma unroll
    for (int fm=0; fm<4; ++fm){
        int m0 = bm + wr + fm*16 + (lane>>4)*4;
        #pragma unroll
        for (int fn=0; fn<2; ++fn){
            int n = bn + wc + fn*16 + (lane&15);
            float bsv = (!WB && bias) ? bias[n] : 0.f;
            #pragma unroll
            for (int j=0; j<4; ++j){
                float v = acc[fm][fn][j] + bsv;
                if (WB) Cb[(size_t)(m0+j)*ldcb + n] = f2b(v);
                else    C [(size_t)(m0+j)*ldc  + n] = v;
            }
        }
    }
}

// ---------------- bf16 MFMA GEMM, 64x64 tile, 8 waves (2x4 of 32x16), 2-phase pipelined ----
// Staging: waves 0-3 fill As (4KB), waves 4-7 fill Bs; one issue per thread per stage.
// SPLIT: blockIdx.x = k-split; partial tile -> C + blockIdx.x*splitStride (bn=0).
// SCAT: remap output rows m(0..511) -> (m>>8)*L_ + CTX_ + (m&255); dual-write fp32 C + bf16 Cb.
template<bool ACC, bool SPLIT, bool SCAT>
__global__ __launch_bounds__(512) void k_mmx64(const u16* __restrict__ A, int lda,
                                               const u16* __restrict__ Bw, int ldb,
                                               float* __restrict__ C, int ldc,
                                               const float* __restrict__ bias, int ksteps,
                                               u16* __restrict__ Cb, int ldcb, int splitStride){
    __shared__ u16 As[2][64*32];
    __shared__ u16 Bs[2][64*32];
    int tid = threadIdx.x;
    int wave = tid >> 6, lane = tid & 63;
    int bm = blockIdx.y*64;
    int bn    = SPLIT ? 0 : blockIdx.x*64;
    int kbase = SPLIT ? blockIdx.x*ksteps*32 : 0;
    int wr = (wave>>2)*32, wc = (wave&3)*16;
    f32x4 acc[2] = {};                     // fm 0..1, fn=0
    int lrow = lane & 15, lk = (lane>>4)*8;
    int w4 = wave & 3;
    int dphys = w4*1024 + lane*16;         // 0..4095 within matrix
    int alog  = dphys ^ (((dphys>>7)&7)<<4);
    int grow  = alog >> 6;                 // 0..63
    int gcol  = (alog & 63) >> 1;
    bool isB = wave >= 4;
    const u16* Sr = isB ? (Bw + (size_t)(bn+grow)*ldb + gcol)
                        : (A  + (size_t)(bm+grow)*lda + gcol);
    u16* dst0 = isB ? &Bs[0][w4*512] : &As[0][w4*512];
    u16* dst1 = isB ? &Bs[1][w4*512] : &As[1][w4*512];
    int aoff[2], boff;
    #pragma unroll
    for (int f=0; f<2; ++f){
        int ra = wr + f*16 + lrow;
        aoff[f] = (ra*64 + lk*2) ^ (((ra>>1)&7)<<4);
    }
    { int rb = wc + lrow; boff = (rb*64 + lk*2) ^ (((rb>>1)&7)<<4); }
    auto stage = [&](int t, int buf){
        gload_lds16(Sr + kbase + t*32, buf ? dst1 : dst0);
    };
    stage(0, 0);
    PIPE_SYNC;
    int cur = 0;
    for (int t = 0; t < ksteps; ++t){
        if (t+1 < ksteps) stage(t+1, cur^1);
        bf16x8 af[2], bfr;
        #pragma unroll
        for (int f=0; f<2; ++f) af[f] = *(const bf16x8*)((const char*)As[cur] + aoff[f]);
        bfr = *(const bf16x8*)((const char*)Bs[cur] + boff);
        #pragma unroll
        for (int fm=0; fm<2; ++fm)
            acc[fm] = __builtin_amdgcn_mfma_f32_16x16x32_bf16(af[fm], bfr, acc[fm], 0,0,0);
        PIPE_SYNC;
        cur ^= 1;
    }
    float* Cout = SPLIT ? (C + (size_t)blockIdx.x*splitStride) : C;
    #pragma unroll
    for (int fm=0; fm<2; ++fm){
        int m0 = bm + wr + fm*16 + (lane>>4)*4;
        int n = bn + wc + (lane&15);
        float bsv = (!SPLIT && bias) ? bias[n] : 0.f;
        #pragma unroll
        for (int j=0; j<4; ++j){
            float v = acc[fm][j] + bsv;
            int m = m0 + j;
            if (SCAT){
                int xrow = (m>>8)*L_ + CTX_ + (m&255);
                C [(size_t)xrow*ldc  + n] = v;
                Cb[(size_t)xrow*ldcb + n] = f2b(v);
            } else {
                size_t off = (size_t)m*ldc + n;
                if (ACC) v += Cout[off];
                Cout[off] = v;
                if (!SPLIT && Cb) Cb[(size_t)m*ldcb + n] = f2b(v);
            }
        }
    }
}

// ---------------- chunked selective scan (CL=16), Δ-proj fused, split-partial sum fused ----------------
// block = (b, c, dgrp of 64 d); thread: dl = tid>>2, sg = (tid&3)*4
__global__ __launch_bounds__(256) void k_scan1(const u16* __restrict__ ub, const float* __restrict__ xdblp,
                                               const float* __restrict__ dtw, const float* __restrict__ dtb,
                                               const float* __restrict__ Alog,
                                               float* __restrict__ hend, float* __restrict__ P){
    __shared__ float sX[CL_*64];      // [16][64]: dt 0:32 | B 32:48 | C 48:64
    __shared__ float sW[64*33];       // dtw [64][32] padded
    __shared__ float sDtb[64];
    __shared__ float sDel[CL_*64];
    __shared__ u16   sU[CL_*64];
    int blk = blockIdx.x;             // B*NC*16 = 2560
    int dgrp = blk & 15;
    int c = (blk>>4) % NC_;
    int b = blk/(16*NC_);
    int d0 = dgrp*64;
    int tid = threadIdx.x;
    size_t rowbase = (size_t)(b*L_ + c*CL_);
    {
        int e = tid*4;
        float4 s4 = *(const float4*)&xdblp[rowbase*64 + e];
        #pragma unroll
        for (int p=1;p<8;++p){
            float4 t4 = *(const float4*)&xdblp[(size_t)p*XDBL_N_ + rowbase*64 + e];
            s4.x+=t4.x; s4.y+=t4.y; s4.z+=t4.z; s4.w+=t4.w;
        }
        *(float4*)&sX[e] = s4;
        int st=e>>6, dd=e&63;
        *(uint2*)&sU[e] = *(const uint2*)&ub[(rowbase+st)*DI_ + d0 + dd];
        int w0 = tid*8, dr = w0>>5, kk = w0&31;
        float4 wa = *(const float4*)&dtw[(size_t)(d0+dr)*DTR_ + kk];
        float4 wb = *(const float4*)&dtw[(size_t)(d0+dr)*DTR_ + kk + 4];
        sW[dr*33+kk+0]=wa.x; sW[dr*33+kk+1]=wa.y; sW[dr*33+kk+2]=wa.z; sW[dr*33+kk+3]=wa.w;
        sW[dr*33+kk+4]=wb.x; sW[dr*33+kk+5]=wb.y; sW[dr*33+kk+6]=wb.z; sW[dr*33+kk+7]=wb.w;
        if (tid < 64) sDtb[tid] = dtb[d0+tid];
    }
    __syncthreads();
    #pragma unroll
    for (int i=0;i<4;++i){
        int idx = tid + i*256;        // 0..1023
        int t = idx>>6, dd = idx&63;
        float acc = sDtb[dd];
        #pragma unroll
        for (int k=0;k<DTR_;++k) acc = fmaf(sX[t*64+k], sW[dd*33+k], acc);
        sDel[idx] = softplusf_(acc);
    }
    __syncthreads();
    int dl = tid>>2, sg = (tid&3)*4;
    int d = d0 + dl;
    float A[4];
    #pragma unroll
    for (int i=0;i<4;++i) A[i] = -__expf(Alog[d*DS_ + sg + i]);
    float h[4] = {0,0,0,0}, Pl[4] = {1.f,1.f,1.f,1.f};
    #pragma unroll
    for (int t=0;t<CL_;++t){
        float delta = sDel[t*64+dl];
        float uu    = b2f(sU[t*64+dl]);
        float du    = delta*uu;
        #pragma unroll
        for (int i=0;i<4;++i){
            float a = __expf(delta*A[i]);
            h[i]  = fmaf(a, h[i], du*sX[t*64 + 32 + sg + i]);
            Pl[i] *= a;
        }
    }
    size_t ob = ((size_t)((b*NC_+c)*DI_) + d)*DS_ + sg;
    *(float4*)&hend[ob] = make_float4(h[0],h[1],h[2],h[3]);
    *(float4*)&P[ob]    = make_float4(Pl[0],Pl[1],Pl[2],Pl[3]);
}

// pass 2: sequential combine across chunks (8-deep load pipelining); hstart in-place into hend
__global__ __launch_bounds__(256) void k_scan2(float* __restrict__ hend, const float* __restrict__ P){
    int g = blockIdx.x*256 + threadIdx.x;        // B*DI*DS = 32768
    int s = g & 15;
    int d = (g>>4) & 1023;
    int b = g>>14;
    size_t base = ((size_t)b*NC_*DI_ + d)*DS_ + s;
    const size_t cs = (size_t)DI_*DS_;
    float h = 0.f;
    for (int c0=0;c0<NC_;c0+=8){
        float he[8], p[8];
        #pragma unroll
        for (int j=0;j<8;++j){ size_t idx = base + (size_t)(c0+j)*cs; he[j]=hend[idx]; p[j]=P[idx]; }
        #pragma unroll
        for (int j=0;j<8;++j){ size_t idx = base + (size_t)(c0+j)*cs; hend[idx]=h; h=fmaf(p[j],h,he[j]); }
    }
}

// pass 3: rerun chunk with correct initial state; Δ fused; partial-sum fused; gate; emit bf16 y
__global__ __launch_bounds__(256) void k_scan3(const u16* __restrict__ ub, const float* __restrict__ xdblp,
                                               const float* __restrict__ dtw, const float* __restrict__ dtb,
                                               const u16* __restrict__ xzb,
                                               const float* __restrict__ Alog, const float* __restrict__ Dsk,
                                               const float* __restrict__ hstart, u16* __restrict__ yb){
    __shared__ float sX[CL_*64];
    __shared__ float sW[64*33];
    __shared__ float sDtb[64];
    __shared__ float sDel[CL_*64];
    __shared__ u16   sU[CL_*64];
    __shared__ float sY[CL_*64];
    int blk = blockIdx.x;
    int dgrp = blk & 15;
    int c = (blk>>4) % NC_;
    int b = blk/(16*NC_);
    int d0 = dgrp*64;
    int tid = threadIdx.x;
    size_t rowbase = (size_t)(b*L_ + c*CL_);
    {
        int e = tid*4;
        float4 s4 = *(const float4*)&xdblp[rowbase*64 + e];
        #pragma unroll
        for (int p=1;p<8;++p){
            float4 t4 = *(const float4*)&xdblp[(size_t)p*XDBL_N_ + rowbase*64 + e];
            s4.x+=t4.x; s4.y+=t4.y; s4.z+=t4.z; s4.w+=t4.w;
        }
        *(float4*)&sX[e] = s4;
        int st=e>>6, dd=e&63;
        *(uint2*)&sU[e] = *(const uint2*)&ub[(rowbase+st)*DI_ + d0 + dd];
        int w0 = tid*8, dr = w0>>5, kk = w0&31;
        float4 wa = *(const float4*)&dtw[(size_t)(d0+dr)*DTR_ + kk];
        float4 wb = *(const float4*)&dtw[(size_t)(d0+dr)*DTR_ + kk + 4];
        sW[dr*33+kk+0]=wa.x; sW[dr*33+kk+1]=wa.y; sW[dr*33+kk+2]=wa.z; sW[dr*33+kk+3]=wa.w;
        sW[dr*33+kk+4]=wb.x; sW[dr*33+kk+5]=wb.y; sW[dr*33+kk+6]=wb.z; sW[dr*33+kk+7]=wb.w;
        if (tid < 64) sDtb[tid] = dtb[d0+tid];
    }
    __syncthreads();
    #pragma unroll
    for (int i=0;i<4;++i){
        int idx = tid + i*256;
        int t = idx>>6, dd = idx&63;
        float acc = sDtb[dd];
        #pragma unroll
        for (int k=0;k<DTR_;++k) acc = fmaf(sX[t*64+k], sW[dd*33+k], acc);
        sDel[idx] = softplusf_(acc);
    }
    __syncthreads();
    int dl = tid>>2, sg = (tid&3)*4;
    int d = d0 + dl;
    float A[4];
    #pragma unroll
    for (int i=0;i<4;++i) A[i] = -__expf(Alog[d*DS_ + sg + i]);
    size_t ib = ((size_t)((b*NC_+c)*DI_) + d)*DS_ + sg;
    float4 h4 = *(const float4*)&hstart[ib];
    float h[4] = {h4.x, h4.y, h4.z, h4.w};
    #pragma unroll
    for (int t=0;t<CL_;++t){
        float delta = sDel[t*64+dl];
        float uu    = b2f(sU[t*64+dl]);
        float du    = delta*uu;
        float yt = 0.f;
        #pragma unroll
        for (int i=0;i<4;++i){
            float a = __expf(delta*A[i]);
            h[i] = fmaf(a, h[i], du*sX[t*64 + 32 + sg + i]);
            yt   = fmaf(h[i], sX[t*64 + 48 + sg + i], yt);
        }
        yt += __shfl_xor(yt, 1);
        yt += __shfl_xor(yt, 2);
        if ((tid&3)==0) sY[t*64+dl] = yt;
    }
    __syncthreads();
    {
        int e = tid*4, st = e>>6, dd = e&63;
        size_t off = (rowbase+st)*DI_ + d0 + dd;
        float4 dskv = *(const float4*)&Dsk[d0+dd];
        uint2 zz = *(const uint2*)&xzb[(rowbase+st)*2048 + DI_ + d0 + dd];
        float z0 = __uint_as_float(zz.x<<16),  z1 = __uint_as_float(zz.x & 0xffff0000u);
        float z2 = __uint_as_float(zz.y<<16),  z3 = __uint_as_float(zz.y & 0xffff0000u);
        float u0 = b2f(sU[e+0]), u1 = b2f(sU[e+1]), u2 = b2f(sU[e+2]), u3 = b2f(sU[e+3]);
        union { u16 us[4]; uint2 q; } o;
        o.us[0] = f2b((sY[e+0] + u0*dskv.x) * siluf_(z0));
        o.us[1] = f2b((sY[e+1] + u1*dskv.y) * siluf_(z1));
        o.us[2] = f2b((sY[e+2] + u2*dskv.z) * siluf_(z2));
        o.us[3] = f2b((sY[e+3] + u3*dskv.w) * siluf_(z3));
        *(uint2*)&yb[off] = o.q;
    }
}

// ---------------- layernorm on target rows only, bf16 out ----------------
__global__ __launch_bounds__(256) void k_ln_tgt(const float* __restrict__ x, const float* __restrict__ g_,
                                                const float* __restrict__ b_, u16* __restrict__ xnb){
    int r = blockIdx.x;                           // 0..B*TGT-1
    int b = r / TGT_, t = r % TGT_;
    const float* row = x + ((size_t)(b*L_+CTX_+t))*DM_;
    int tid = threadIdx.x;
    float2 v = *(const float2*)&row[tid*2];
    float s = v.x+v.y, sq = v.x*v.x+v.y*v.y;
    #pragma unroll
    for (int off=32; off; off>>=1){ s += __shfl_down(s,off); sq += __shfl_down(sq,off); }
    __shared__ float ss[4], ssq[4];
    int w = tid>>6, ln = tid&63;
    if (ln==0){ ss[w]=s; ssq[w]=sq; }
    __syncthreads();
    if (tid==0){
        float S=ss[0]+ss[1]+ss[2]+ss[3], Q=ssq[0]+ssq[1]+ssq[2]+ssq[3];
        float mu = S/(float)DM_;
        float var = Q/(float)DM_ - mu*mu;
        ss[0]=mu; ssq[0]=rsqrtf(var+1e-5f);
    }
    __syncthreads();
    float mu=ss[0], rs=ssq[0];
    xnb[(size_t)r*DM_ + tid*2+0] = f2b((v.x-mu)*rs*g_[tid*2+0] + b_[tid*2+0]);
    xnb[(size_t)r*DM_ + tid*2+1] = f2b((v.y-mu)*rs*g_[tid*2+1] + b_[tid*2+1]);
}

// ---------------- host launch ----------------
extern "C" void kernel_launch(void* const* d_in, const int* in_sizes, int n_in,
                              void* d_out, int out_size, void* d_ws, size_t ws_size,
                              hipStream_t stream) {
    const float* ctx    = (const float*)d_in[0];
    const float* te     = (const float*)d_in[1];
    const float* ve     = (const float*)d_in[2];
    const float* pos_w  = (const float*)d_in[4];
    const float* pos_b  = (const float*)d_in[5];
    const float* outp_w = (const float*)d_in[6];
    const float* outp_b = (const float*)d_in[7];
    const float* ln_g   = (const float*)d_in[8];
    const float* ln_b   = (const float*)d_in[9];
    const float* in_w   = (const float*)d_in[10];
    const float* conv_w = (const float*)d_in[11];
    const float* conv_b = (const float*)d_in[12];
    const float* xproj_w= (const float*)d_in[13];
    const float* dt_w   = (const float*)d_in[14];
    const float* dt_b   = (const float*)d_in[15];
    const float* A_log  = (const float*)d_in[16];
    const float* D_skip = (const float*)d_in[17];
    const float* out_w  = (const float*)d_in[18];
    float* out = (float*)d_out;

    float* ws    = (float*)d_ws;
    float* x     = ws;                       // 1,310,720
    float* hend  = x     + 1310720;          // 2,621,440 (B*NC*DI*DS)
    float* P     = hend  + 2621440;          // 2,621,440
    float* xdblp = P     + 2621440;          // 1,310,720 (8 split partials)
    u16*  xb    = (u16*)(xdblp + 1310720);   // 1,310,720 u16
    u16*  tcb   = xb    + 1310720;           //   524,288
    u16*  yb    = tcb   + 524288;            // 2,621,440
    u16*  xnb   = yb    + 2621440;           //   262,144
    u16*  ub    = xnb   + 262144;            // 2,621,440
    u16*  xzb   = ub    + 2621440;           // 5,242,880
    u16*  inwb  = xzb   + 5242880;           // 2,097,152
    u16*  outwb = inwb  + 2097152;           // 1,048,576
    u16*  poswb = outwb + 1048576;           //   524,288
    u16*  outpwb= poswb + 524288;            //   262,144
    u16*  xpwb  = outpwb+ 262144;            //   131,072

    k_init<<<3520, 256, 0, stream>>>(in_w, out_w, pos_w, outp_w, xproj_w,
                                     inwb, outwb, poswb, outpwb, xpwb,
                                     ctx, te, ve, x, xb, tcb);
    // pos projection, scattered directly into x/xb target rows
    k_mmx64<false,false,true><<<dim3(8,8), 512, 0, stream>>>(tcb, 2*DM_, poswb, 2*DM_, x, DM_, pos_b, 32, xb, DM_, 0);

    for (int i=0;i<NL_;++i){
        const u16*   inwbi  = inwb + (size_t)i*2*DI_*DM_;
        const float* cw     = conv_w  + (size_t)i*DI_*DCONV_;
        const float* cb     = conv_b  + (size_t)i*DI_;
        const u16*   xpwbi  = xpwb + (size_t)i*(DTR_+2*DS_)*DI_;
        const float* dtw    = dt_w    + (size_t)i*DI_*DTR_;
        const float* dtb    = dt_b    + (size_t)i*DI_;
        const float* Ai     = A_log   + (size_t)i*DI_*DS_;
        const float* Dsk    = D_skip  + (size_t)i*DI_;
        const u16*   outwbi = outwb + (size_t)i*DM_*DI_;

        k_mmx<true><<<dim3(16,20), 512, 0, stream>>>(xb, DM_, inwbi, DM_, nullptr, 0, nullptr, DM_, xzb, 2*DI_);
        k_conv_silu<<<2560, 256, 0, stream>>>(xzb, cw, cb, ub);
        k_mmx64<false,true,false><<<dim3(8,40), 512, 0, stream>>>(ub, DI_, xpwbi, DI_, xdblp, 64, nullptr, 4, nullptr, 0, XDBL_N_);
        k_scan1<<<2560, 256, 0, stream>>>(ub, xdblp, dtw, dtb, Ai, hend, P);
        k_scan2<<<128, 256, 0, stream>>>(hend, P);
        k_scan3<<<2560, 256, 0, stream>>>(ub, xdblp, dtw, dtb, xzb, Ai, Dsk, hend, yb);
        k_mmx64<true,false,false><<<dim3(8,40), 512, 0, stream>>>(yb, DI_, outwbi, DI_, x, DM_, nullptr, 32, xb, DM_, 0);
    }

    k_ln_tgt<<<512, 256, 0, stream>>>(x, ln_g, ln_b, xnb);
    k_mmx64<false,false,false><<<dim3(8,8), 512, 0, stream>>>(xnb, DM_, outpwb, DM_, out, DM_, outp_b, 16, nullptr, 0, 0);
}